// Round 7
// baseline (404.321 us; speedup 1.0000x reference)
//
#include <hip/hip_runtime.h>
#include <hip/hip_fp16.h>

#define N_NODES 100000
#define N_EDGES 1600000
#define IN_F    128
#define HID_F   256
#define OUT_F   160
#define BN_EPS  1e-5f

#define EPB     4096                         // edges per chunk
#define NCHUNK  ((N_EDGES + EPB - 1) / EPB)  // 391
#define NPP     (N_NODES / 8)                // 12500 nodes per XCD partition
#define SCHUNK  ((N_NODES + 1023) / 1024)    // 98 scan chunks
#define NSUB    (N_NODES / 32)               // 3125 node-subtiles (exact)

typedef __attribute__((ext_vector_type(8))) short bf16x8;
typedef __attribute__((ext_vector_type(4))) float f32x4;

static __device__ inline unsigned short f2bf(float x) {
  unsigned u = __float_as_uint(x);
  return (unsigned short)((u + 0x7fffu + ((u >> 16) & 1u)) >> 16);
}
static __device__ inline unsigned f2bf_pair(float lo, float hi) {
  return (unsigned)f2bf(lo) | ((unsigned)f2bf(hi) << 16);
}
static __device__ inline float bf_lo(unsigned u) {
  return __uint_as_float(u << 16);
}
static __device__ inline float bf_hi(unsigned u) {
  return __uint_as_float(u & 0xffff0000u);
}

// ---------------------------------------------------------------------------
// K0: XCD-partitioned histogram (cursor pre-zeroed)
// ---------------------------------------------------------------------------
__global__ __launch_bounds__(256) void k_hist(const int* __restrict__ dst,
                                              int* __restrict__ cursor) {
  const int p = blockIdx.x & 7;
  const int e0 = (blockIdx.x >> 3) * EPB + threadIdx.x;
  const int lo = p * NPP, hi = lo + NPP;
#pragma unroll
  for (int i = 0; i < EPB / 256; ++i) {
    int e = e0 + i * 256;
    if (e < N_EDGES) {
      int d = dst[e];
      if (d >= lo && d < hi) atomicAdd(&cursor[d], 1);
    }
  }
}

// ---------------------------------------------------------------------------
// K1a: per-chunk scan (98 blocks x 1024)
// ---------------------------------------------------------------------------
__global__ __launch_bounds__(1024) void k_scan1(const int* __restrict__ cursor,
                                                int* __restrict__ offs,
                                                int* __restrict__ totals) {
  __shared__ int wsum[16];
  __shared__ int ctot;
  const int tid = threadIdx.x, lane = tid & 63, wid = tid >> 6;
  int i = blockIdx.x * 1024 + tid;
  int v = (i < N_NODES) ? cursor[i] : 0;
  int x = v;
#pragma unroll
  for (int off = 1; off < 64; off <<= 1) {
    int t = __shfl_up(x, off, 64);
    if (lane >= off) x += t;
  }
  if (lane == 63) wsum[wid] = x;
  __syncthreads();
  if (wid == 0) {
    int s = (lane < 16) ? wsum[lane] : 0;
    int y = s;
#pragma unroll
    for (int off = 1; off < 16; off <<= 1) {
      int t = __shfl_up(y, off, 64);
      if (lane >= off) y += t;
    }
    if (lane < 16) wsum[lane] = y - s;
    if (lane == 15) ctot = y;
  }
  __syncthreads();
  if (i < N_NODES) offs[i] = wsum[wid] + (x - v);
  if (tid == 0) totals[blockIdx.x] = ctot;
}

// ---------------------------------------------------------------------------
// K1b: scan 98 chunk totals -> bases
// ---------------------------------------------------------------------------
__global__ __launch_bounds__(128) void k_scan2(const int* __restrict__ totals,
                                               int* __restrict__ bases) {
  __shared__ int w0t;
  const int tid = threadIdx.x, lane = tid & 63;
  int t = (tid < SCHUNK) ? totals[tid] : 0;
  int x = t;
#pragma unroll
  for (int off = 1; off < 64; off <<= 1) {
    int q = __shfl_up(x, off, 64);
    if (lane >= off) x += q;
  }
  if (tid == 63) w0t = x;
  __syncthreads();
  int excl = x - t + ((tid >= 64) ? w0t : 0);
  if (tid < SCHUNK) bases[tid] = excl;
}

// ---------------------------------------------------------------------------
// K1c: add bases -> final exclusive offsets in offs AND cursor
// ---------------------------------------------------------------------------
__global__ __launch_bounds__(256) void k_scan3(int* __restrict__ offs,
                                               int* __restrict__ cursor,
                                               const int* __restrict__ bases) {
  int i = blockIdx.x * 256 + threadIdx.x;
  if (i < N_NODES) {
    int o = offs[i] + bases[i >> 10];
    offs[i] = o;
    cursor[i] = o;
  }
  if (i == 0) offs[N_NODES] = N_EDGES;
}

// ---------------------------------------------------------------------------
// K2: XCD-partitioned place. pairs[slot] = (src<<15) | (fp16(w) & 0x7fff)
// ---------------------------------------------------------------------------
__global__ __launch_bounds__(256) void k_place(
    const int* __restrict__ src, const int* __restrict__ dst,
    const float* __restrict__ ew, int* __restrict__ cursor,
    unsigned* __restrict__ pairs) {
  const int p = blockIdx.x & 7;
  const int e0 = (blockIdx.x >> 3) * EPB + threadIdx.x;
  const int lo = p * NPP, hi = lo + NPP;
#pragma unroll
  for (int i = 0; i < EPB / 256; ++i) {
    int e = e0 + i * 256;
    if (e < N_EDGES) {
      int d = dst[e];
      if (d >= lo && d < hi) {
        unsigned hb = (unsigned)__half_as_ushort(__float2half(ew[e])) & 0x7fffu;
        int slot = atomicAdd(&cursor[d], 1);
        pairs[slot] = ((unsigned)src[e] << 15) | hb;
      }
    }
  }
}

// ---------------------------------------------------------------------------
// K3: feat fp32 -> bf16 into A1 columns 0..127 (row stride 256 bf16)
// ---------------------------------------------------------------------------
__global__ __launch_bounds__(256) void k_convert(
    const float* __restrict__ feat, unsigned* __restrict__ A1u) {
  long long idx = (long long)blockIdx.x * 256 + threadIdx.x;
  long long fidx = idx * 8;
  if (fidx >= (long long)N_NODES * IN_F) return;
  int node = (int)(fidx >> 7);
  int c0 = (int)(fidx & 127);
  float4 f0 = *reinterpret_cast<const float4*>(feat + fidx);
  float4 f1 = *reinterpret_cast<const float4*>(feat + fidx + 4);
  uint4 o;
  o.x = f2bf_pair(f0.x, f0.y);
  o.y = f2bf_pair(f0.z, f0.w);
  o.z = f2bf_pair(f1.x, f1.y);
  o.w = f2bf_pair(f1.z, f1.w);
  *reinterpret_cast<uint4*>(A1u + (size_t)node * 128 + (c0 >> 1)) = o;
}

// ---------------------------------------------------------------------------
// K4: W1T[c][k] = bf16( k<128 ? Wself[k][c] : Wneigh[k-128][c] )
// ---------------------------------------------------------------------------
__global__ __launch_bounds__(256) void k_prepw(
    const float* __restrict__ Wself, const float* __restrict__ Wneigh,
    unsigned short* __restrict__ W1T) {
  int c = blockIdx.x;
  int k = threadIdx.x;
  float v = (k < 128) ? Wself[(size_t)k * HID_F + c]
                      : Wneigh[(size_t)(k - 128) * HID_F + c];
  W1T[(size_t)c * 256 + k] = f2bf(v);
}

// ---------------------------------------------------------------------------
// K5: pull-gather, 4-edge-parallel (validated round 5)
// ---------------------------------------------------------------------------
__global__ __launch_bounds__(256) void k_gather(
    const int* __restrict__ offs, const unsigned* __restrict__ pairs,
    unsigned* __restrict__ A1u) {
  int node = blockIdx.x * 4 + (threadIdx.x >> 6);
  if (node >= N_NODES) return;
  const int lane = threadIdx.x & 63;
  const int g = lane >> 4;
  const int cl = lane & 15;
  const int start = offs[node], end = offs[node + 1];
  const int deg = end - start;

  float acc[8] = {0.f, 0.f, 0.f, 0.f, 0.f, 0.f, 0.f, 0.f};

  for (int k0 = start; k0 < end; k0 += 64) {
    unsigned pr = 0;
    if (k0 + lane < end) pr = pairs[k0 + lane];
    const int cnt = min(64, end - k0);
    const int nsteps = (cnt + 3) >> 2;
    for (int t = 0; t < nsteps; ++t) {
      unsigned uu = (unsigned)__shfl((int)pr, 4 * t + g, 64);
      int s = (int)(uu >> 15);
      float w = __half2float(__ushort_as_half((unsigned short)(uu & 0x7fffu)));
      uint4 f = *reinterpret_cast<const uint4*>(A1u + (size_t)s * 128 + cl * 4);
      acc[0] = fmaf(w, bf_lo(f.x), acc[0]);
      acc[1] = fmaf(w, bf_hi(f.x), acc[1]);
      acc[2] = fmaf(w, bf_lo(f.y), acc[2]);
      acc[3] = fmaf(w, bf_hi(f.y), acc[3]);
      acc[4] = fmaf(w, bf_lo(f.z), acc[4]);
      acc[5] = fmaf(w, bf_hi(f.z), acc[5]);
      acc[6] = fmaf(w, bf_lo(f.w), acc[6]);
      acc[7] = fmaf(w, bf_hi(f.w), acc[7]);
    }
  }

#pragma unroll
  for (int i = 0; i < 8; ++i) {
    acc[i] += __shfl_xor(acc[i], 16, 64);
    acc[i] += __shfl_xor(acc[i], 32, 64);
  }

  if (g == 0) {
    const float inv = (deg > 0) ? (1.0f / (float)deg) : 0.f;
    uint4 o;
    o.x = f2bf_pair(acc[0] * inv, acc[1] * inv);
    o.y = f2bf_pair(acc[2] * inv, acc[3] * inv);
    o.z = f2bf_pair(acc[4] * inv, acc[5] * inv);
    o.w = f2bf_pair(acc[6] * inv, acc[7] * inv);
    *reinterpret_cast<uint4*>(A1u + (size_t)node * 128 + 64 + cl * 4) = o;
  }
}

// ---------------------------------------------------------------------------
// K6: GEMM1, operand-swapped, LDS-free, barrier-free.
// Wave = 32 nodes x 128 h (h-half).  D = W1 (A-op, rows=h) x A1^T (B-op,
// cols=nodes).  C-layout: col(l16)=node, row(lk*4+r)=h  [m89].
// y stored standard [node][256] bf16 via packed uint2 (4 consecutive h).
// BN stats -> per-wave slab colpart[gwid][256] (no atomics).
// ---------------------------------------------------------------------------
__global__ __launch_bounds__(256) void k_gemm1(
    const unsigned short* __restrict__ A1, const unsigned short* __restrict__ W1T,
    const float* __restrict__ bias, unsigned short* __restrict__ y,
    float* __restrict__ colpart) {
  const int lane = threadIdx.x & 63;
  const int wid = threadIdx.x >> 6;
  const int l16 = lane & 15, lk = lane >> 4;
  const int hhalf = wid & 1;                       // 0: h 0..127, 1: 128..255
  const int nbase = (blockIdx.x * 2 + (wid >> 1)) * 32;
  if (nbase >= N_NODES) return;
  const int hb = hhalf * 128;

  f32x4 acc[8][2];
#pragma unroll
  for (int m = 0; m < 8; ++m)
#pragma unroll
    for (int n = 0; n < 2; ++n) acc[m][n] = (f32x4){0.f, 0.f, 0.f, 0.f};

#pragma unroll
  for (int ks = 0; ks < 8; ++ks) {
    const int k0 = ks * 32;
    bf16x8 bf0 = *reinterpret_cast<const bf16x8*>(
        A1 + (size_t)(nbase + l16) * 256 + k0 + lk * 8);
    bf16x8 bf1 = *reinterpret_cast<const bf16x8*>(
        A1 + (size_t)(nbase + 16 + l16) * 256 + k0 + lk * 8);
#pragma unroll
    for (int m = 0; m < 8; ++m) {
      bf16x8 af = *reinterpret_cast<const bf16x8*>(
          W1T + (size_t)(hb + m * 16 + l16) * 256 + k0 + lk * 8);
      acc[m][0] = __builtin_amdgcn_mfma_f32_16x16x32_bf16(af, bf0, acc[m][0], 0, 0, 0);
      acc[m][1] = __builtin_amdgcn_mfma_f32_16x16x32_bf16(af, bf1, acc[m][1], 0, 0, 0);
    }
  }

  // epilogue: bias + relu + packed y store + per-wave BN partials
  const int gwid = blockIdx.x * 4 + wid;   // = j*2 + hhalf, j = node subtile
#pragma unroll
  for (int m = 0; m < 8; ++m) {
    const float4 b4 = *reinterpret_cast<const float4*>(bias + hb + m * 16 + lk * 4);
    float s0 = 0.f, s1 = 0.f, s2 = 0.f, s3 = 0.f;
    float q0 = 0.f, q1 = 0.f, q2 = 0.f, q3 = 0.f;
#pragma unroll
    for (int n = 0; n < 2; ++n) {
      float t0 = fmaxf(acc[m][n][0] + b4.x, 0.f);
      float t1 = fmaxf(acc[m][n][1] + b4.y, 0.f);
      float t2 = fmaxf(acc[m][n][2] + b4.z, 0.f);
      float t3 = fmaxf(acc[m][n][3] + b4.w, 0.f);
      uint2 pk;
      pk.x = f2bf_pair(t0, t1);
      pk.y = f2bf_pair(t2, t3);
      *reinterpret_cast<uint2*>(
          y + (size_t)(nbase + n * 16 + l16) * 256 + hb + m * 16 + lk * 4) = pk;
      s0 += t0; s1 += t1; s2 += t2; s3 += t3;
      q0 += t0 * t0; q1 += t1 * t1; q2 += t2 * t2; q3 += t3 * t3;
    }
    float sv[4] = {s0, s1, s2, s3};
    float qv[4] = {q0, q1, q2, q3};
#pragma unroll
    for (int r = 0; r < 4; ++r) {
      float s = sv[r], q = qv[r];
      s += __shfl_xor(s, 1, 64);  s += __shfl_xor(s, 2, 64);
      s += __shfl_xor(s, 4, 64);  s += __shfl_xor(s, 8, 64);
      q += __shfl_xor(q, 1, 64);  q += __shfl_xor(q, 2, 64);
      q += __shfl_xor(q, 4, 64);  q += __shfl_xor(q, 8, 64);
      if (l16 == 0) {
        int hl = m * 16 + lk * 4 + r;     // 0..127
        colpart[(size_t)gwid * 256 + hl] = s;
        colpart[(size_t)gwid * 256 + 128 + hl] = q;
      }
    }
  }
}

// ---------------------------------------------------------------------------
// K6b: reduce colpart -> colsum/colsq (colsum/colsq pre-zeroed)
// ---------------------------------------------------------------------------
__global__ __launch_bounds__(256) void k_redstats(
    const float* __restrict__ colpart, float* __restrict__ colsum,
    float* __restrict__ colsq) {
  const int h = threadIdx.x;          // 0..255
  const int half = h >> 7, hl = h & 127;
  float s = 0.f, q = 0.f;
  for (int j = blockIdx.x; j < NSUB; j += gridDim.x) {
    const float* row = colpart + (size_t)(2 * j + half) * 256;
    s += row[hl];
    q += row[128 + hl];
  }
  atomicAdd(&colsum[h], s);
  atomicAdd(&colsq[h], q);
}

// ---------------------------------------------------------------------------
// K7: BN fold -> W2T[o][h] bf16 (o padded to 192), b2[o] f32
// ---------------------------------------------------------------------------
__global__ __launch_bounds__(256) void k_finalize(
    const float* __restrict__ colsum, const float* __restrict__ colsq,
    const float* __restrict__ gamma, const float* __restrict__ beta,
    const float* __restrict__ fcW, const float* __restrict__ fcb,
    unsigned short* __restrict__ W2T, float* __restrict__ b2) {
  const float invN = 1.0f / (float)N_NODES;
  if (blockIdx.x < 192) {
    int o = blockIdx.x, h = threadIdx.x;
    unsigned short v = 0;
    if (o < OUT_F) {
      float mu = colsum[h] * invN;
      float var = colsq[h] * invN - mu * mu;
      float rs = rsqrtf(var + BN_EPS) * gamma[h];
      v = f2bf(fcW[(size_t)h * OUT_F + o] * rs);
    }
    W2T[(size_t)o * 256 + h] = v;
  } else if (threadIdx.x < OUT_F) {
    int o = threadIdx.x;
    float acc = fcb[o];
    for (int h = 0; h < HID_F; ++h) {
      float mu = colsum[h] * invN;
      float var = colsq[h] * invN - mu * mu;
      float rs = rsqrtf(var + BN_EPS) * gamma[h];
      acc += (beta[h] - mu * rs) * fcW[(size_t)h * OUT_F + o];
    }
    b2[o] = acc;
  }
}

// ---------------------------------------------------------------------------
// K8: GEMM2, operand-swapped, LDS-free, barrier-free.
// Wave = 32 nodes x 160 o (10 m-frags exactly).  out store = float4,
// full-line coalesced (per node: 4 lk-chunks x 16 B = 64 B).
// ---------------------------------------------------------------------------
__global__ __launch_bounds__(256) void k_gemm2(
    const unsigned short* __restrict__ y, const unsigned short* __restrict__ W2T,
    const float* __restrict__ b2, float* __restrict__ out) {
  const int lane = threadIdx.x & 63;
  const int wid = threadIdx.x >> 6;
  const int l16 = lane & 15, lk = lane >> 4;
  const int nbase = (blockIdx.x * 4 + wid) * 32;
  if (nbase >= N_NODES) return;

  f32x4 acc[10][2];
#pragma unroll
  for (int m = 0; m < 10; ++m)
#pragma unroll
    for (int n = 0; n < 2; ++n) acc[m][n] = (f32x4){0.f, 0.f, 0.f, 0.f};

#pragma unroll
  for (int ks = 0; ks < 8; ++ks) {
    const int k0 = ks * 32;
    bf16x8 bf0 = *reinterpret_cast<const bf16x8*>(
        y + (size_t)(nbase + l16) * 256 + k0 + lk * 8);
    bf16x8 bf1 = *reinterpret_cast<const bf16x8*>(
        y + (size_t)(nbase + 16 + l16) * 256 + k0 + lk * 8);
#pragma unroll
    for (int m = 0; m < 10; ++m) {
      bf16x8 af = *reinterpret_cast<const bf16x8*>(
          W2T + (size_t)(m * 16 + l16) * 256 + k0 + lk * 8);
      acc[m][0] = __builtin_amdgcn_mfma_f32_16x16x32_bf16(af, bf0, acc[m][0], 0, 0, 0);
      acc[m][1] = __builtin_amdgcn_mfma_f32_16x16x32_bf16(af, bf1, acc[m][1], 0, 0, 0);
    }
  }

#pragma unroll
  for (int m = 0; m < 10; ++m) {
    const float4 b4 = *reinterpret_cast<const float4*>(b2 + m * 16 + lk * 4);
#pragma unroll
    for (int n = 0; n < 2; ++n) {
      float4 v;
      v.x = acc[m][n][0] + b4.x;
      v.y = acc[m][n][1] + b4.y;
      v.z = acc[m][n][2] + b4.z;
      v.w = acc[m][n][3] + b4.w;
      *reinterpret_cast<float4*>(
          out + (size_t)(nbase + n * 16 + l16) * OUT_F + m * 16 + lk * 4) = v;
    }
  }
}

// ---------------------------------------------------------------------------
extern "C" void kernel_launch(void* const* d_in, const int* in_sizes, int n_in,
                              void* d_out, int out_size, void* d_ws,
                              size_t ws_size, hipStream_t stream) {
  const float* feat   = (const float*)d_in[0];
  const int*   src    = (const int*)d_in[1];
  const int*   dst    = (const int*)d_in[2];
  const float* ew     = (const float*)d_in[3];
  const float* Wself  = (const float*)d_in[4];
  const float* Wneigh = (const float*)d_in[5];
  const float* bias   = (const float*)d_in[6];
  const float* gamma  = (const float*)d_in[7];
  const float* beta   = (const float*)d_in[8];
  const float* fcW    = (const float*)d_in[9];
  const float* fcb    = (const float*)d_in[10];
  float* out = (float*)d_out;

  char* ws = (char*)d_ws;
  // layout (bytes):
  //   [0,        400,000)   cursor  N i32            (zeroed)
  //   [400,000,  401,024)   colsum  256 f32          (zeroed)
  //   [401,024,  402,048)   colsq   256 f32          (zeroed)
  //   [402,048,  802,052)   offs    (N+1) i32
  //   [802,304,  802,696)   totals  98 i32
  //   [802,816,  803,208)   bases   98 i32
  //   [803,328,  7,203,328) pairs   E u32
  //   [7,203,328, 58,403,328)  A1      N*256 bf16 (feat | neigh)
  //   [58,403,328,58,534,400)  W1T     256*256 bf16
  //   [58,534,400,58,632,704)  W2T     192*256 bf16
  //   [58,632,704,58,633,344)  b2      160 f32
  //   [58,633,344,109,833,344) y       N*256 bf16
  //   [109,833,344,116,235,392) colpart 6252*256 f32
  int*            cursor  = (int*)(ws + 0);
  float*          colsum  = (float*)(ws + 400000);
  float*          colsq   = (float*)(ws + 401024);
  int*            offs    = (int*)(ws + 402048);
  int*            totals  = (int*)(ws + 802304);
  int*            bases   = (int*)(ws + 802816);
  unsigned*       pairs   = (unsigned*)(ws + 803328);
  unsigned*       A1u     = (unsigned*)(ws + 7203328);
  unsigned short* A1      = (unsigned short*)(ws + 7203328);
  unsigned short* W1T     = (unsigned short*)(ws + 58403328);
  unsigned short* W2T     = (unsigned short*)(ws + 58534400);
  float*          b2      = (float*)(ws + 58632704);
  unsigned short* y       = (unsigned short*)(ws + 58633344);
  float*          colpart = (float*)(ws + 109833344);

  hipMemsetAsync(ws, 0, 402048, stream);

  dim3 b256(256);
  k_convert<<<dim3((N_NODES * IN_F / 8 + 255) / 256), b256, 0, stream>>>(
      feat, A1u);
  k_prepw<<<dim3(256), b256, 0, stream>>>(Wself, Wneigh, W1T);
  k_hist<<<dim3(NCHUNK * 8), b256, 0, stream>>>(dst, cursor);
  k_scan1<<<dim3(SCHUNK), dim3(1024), 0, stream>>>(cursor, offs, totals);
  k_scan2<<<dim3(1), dim3(128), 0, stream>>>(totals, bases);
  k_scan3<<<dim3((N_NODES + 255) / 256), b256, 0, stream>>>(
      offs, cursor, bases);
  k_place<<<dim3(NCHUNK * 8), b256, 0, stream>>>(
      src, dst, ew, cursor, pairs);
  k_gather<<<dim3((N_NODES + 3) / 4), b256, 0, stream>>>(offs, pairs, A1u);
  k_gemm1<<<dim3((N_NODES + 63) / 64), b256, 0, stream>>>(
      A1, W1T, bias, y, colpart);
  k_redstats<<<dim3(64), b256, 0, stream>>>(colpart, colsum, colsq);
  k_finalize<<<dim3(193), b256, 0, stream>>>(
      colsum, colsq, gamma, beta, fcW, fcb, W2T, b2);
  k_gemm2<<<dim3((N_NODES + 127) / 128), b256, 0, stream>>>(
      y, W2T, b2, out);
}

// Round 8
// 333.070 us; speedup vs baseline: 1.2139x; 1.2139x over previous
//
#include <hip/hip_runtime.h>
#include <hip/hip_fp16.h>

#define N_NODES 100000
#define N_EDGES 1600000
#define IN_F    128
#define HID_F   256
#define OUT_F   160
#define BN_EPS  1e-5f

#define EPB     4096                         // edges per chunk
#define NCHUNK  ((N_EDGES + EPB - 1) / EPB)  // 391
#define NPP     (N_NODES / 8)                // 12500 nodes per XCD partition
#define SCHUNK  ((N_NODES + 1023) / 1024)    // 98 scan chunks
#define NSUB    (N_NODES / 32)               // 3125 32-node tiles (exact)
#define G1_GRID 512
#define NT2     ((N_NODES + 63) / 64)        // 1563 64-node tiles
#define G2_GRID 512

typedef __attribute__((ext_vector_type(8))) short bf16x8;
typedef __attribute__((ext_vector_type(4))) float f32x4;

static __device__ inline unsigned short f2bf(float x) {
  unsigned u = __float_as_uint(x);
  return (unsigned short)((u + 0x7fffu + ((u >> 16) & 1u)) >> 16);
}
static __device__ inline unsigned f2bf_pair(float lo, float hi) {
  return (unsigned)f2bf(lo) | ((unsigned)f2bf(hi) << 16);
}
static __device__ inline float bf_lo(unsigned u) {
  return __uint_as_float(u << 16);
}
static __device__ inline float bf_hi(unsigned u) {
  return __uint_as_float(u & 0xffff0000u);
}

// ---------------------------------------------------------------------------
// K0: XCD-partitioned histogram (cursor pre-zeroed)
// ---------------------------------------------------------------------------
__global__ __launch_bounds__(256) void k_hist(const int* __restrict__ dst,
                                              int* __restrict__ cursor) {
  const int p = blockIdx.x & 7;
  const int e0 = (blockIdx.x >> 3) * EPB + threadIdx.x;
  const int lo = p * NPP, hi = lo + NPP;
#pragma unroll
  for (int i = 0; i < EPB / 256; ++i) {
    int e = e0 + i * 256;
    if (e < N_EDGES) {
      int d = dst[e];
      if (d >= lo && d < hi) atomicAdd(&cursor[d], 1);
    }
  }
}

// ---------------------------------------------------------------------------
// K1a: per-chunk scan (98 blocks x 1024)
// ---------------------------------------------------------------------------
__global__ __launch_bounds__(1024) void k_scan1(const int* __restrict__ cursor,
                                                int* __restrict__ offs,
                                                int* __restrict__ totals) {
  __shared__ int wsum[16];
  __shared__ int ctot;
  const int tid = threadIdx.x, lane = tid & 63, wid = tid >> 6;
  int i = blockIdx.x * 1024 + tid;
  int v = (i < N_NODES) ? cursor[i] : 0;
  int x = v;
#pragma unroll
  for (int off = 1; off < 64; off <<= 1) {
    int t = __shfl_up(x, off, 64);
    if (lane >= off) x += t;
  }
  if (lane == 63) wsum[wid] = x;
  __syncthreads();
  if (wid == 0) {
    int s = (lane < 16) ? wsum[lane] : 0;
    int y = s;
#pragma unroll
    for (int off = 1; off < 16; off <<= 1) {
      int t = __shfl_up(y, off, 64);
      if (lane >= off) y += t;
    }
    if (lane < 16) wsum[lane] = y - s;
    if (lane == 15) ctot = y;
  }
  __syncthreads();
  if (i < N_NODES) offs[i] = wsum[wid] + (x - v);
  if (tid == 0) totals[blockIdx.x] = ctot;
}

// ---------------------------------------------------------------------------
// K1b: scan 98 chunk totals -> bases
// ---------------------------------------------------------------------------
__global__ __launch_bounds__(128) void k_scan2(const int* __restrict__ totals,
                                               int* __restrict__ bases) {
  __shared__ int w0t;
  const int tid = threadIdx.x, lane = tid & 63;
  int t = (tid < SCHUNK) ? totals[tid] : 0;
  int x = t;
#pragma unroll
  for (int off = 1; off < 64; off <<= 1) {
    int q = __shfl_up(x, off, 64);
    if (lane >= off) x += q;
  }
  if (tid == 63) w0t = x;
  __syncthreads();
  int excl = x - t + ((tid >= 64) ? w0t : 0);
  if (tid < SCHUNK) bases[tid] = excl;
}

// ---------------------------------------------------------------------------
// K1c: add bases -> final exclusive offsets in offs AND cursor
// ---------------------------------------------------------------------------
__global__ __launch_bounds__(256) void k_scan3(int* __restrict__ offs,
                                               int* __restrict__ cursor,
                                               const int* __restrict__ bases) {
  int i = blockIdx.x * 256 + threadIdx.x;
  if (i < N_NODES) {
    int o = offs[i] + bases[i >> 10];
    offs[i] = o;
    cursor[i] = o;
  }
  if (i == 0) offs[N_NODES] = N_EDGES;
}

// ---------------------------------------------------------------------------
// K2: XCD-partitioned place. pairs[slot] = (src<<15) | (fp16(w) & 0x7fff)
// ---------------------------------------------------------------------------
__global__ __launch_bounds__(256) void k_place(
    const int* __restrict__ src, const int* __restrict__ dst,
    const float* __restrict__ ew, int* __restrict__ cursor,
    unsigned* __restrict__ pairs) {
  const int p = blockIdx.x & 7;
  const int e0 = (blockIdx.x >> 3) * EPB + threadIdx.x;
  const int lo = p * NPP, hi = lo + NPP;
#pragma unroll
  for (int i = 0; i < EPB / 256; ++i) {
    int e = e0 + i * 256;
    if (e < N_EDGES) {
      int d = dst[e];
      if (d >= lo && d < hi) {
        unsigned hb = (unsigned)__half_as_ushort(__float2half(ew[e])) & 0x7fffu;
        int slot = atomicAdd(&cursor[d], 1);
        pairs[slot] = ((unsigned)src[e] << 15) | hb;
      }
    }
  }
}

// ---------------------------------------------------------------------------
// K3: feat fp32 -> bf16 into A1 columns 0..127 (row stride 256 bf16)
// ---------------------------------------------------------------------------
__global__ __launch_bounds__(256) void k_convert(
    const float* __restrict__ feat, unsigned* __restrict__ A1u) {
  long long idx = (long long)blockIdx.x * 256 + threadIdx.x;
  long long fidx = idx * 8;
  if (fidx >= (long long)N_NODES * IN_F) return;
  int node = (int)(fidx >> 7);
  int c0 = (int)(fidx & 127);
  float4 f0 = *reinterpret_cast<const float4*>(feat + fidx);
  float4 f1 = *reinterpret_cast<const float4*>(feat + fidx + 4);
  uint4 o;
  o.x = f2bf_pair(f0.x, f0.y);
  o.y = f2bf_pair(f0.z, f0.w);
  o.z = f2bf_pair(f1.x, f1.y);
  o.w = f2bf_pair(f1.z, f1.w);
  *reinterpret_cast<uint4*>(A1u + (size_t)node * 128 + (c0 >> 1)) = o;
}

// ---------------------------------------------------------------------------
// K4: W1T[c][k] = bf16( k<128 ? Wself[k][c] : Wneigh[k-128][c] )
// ---------------------------------------------------------------------------
__global__ __launch_bounds__(256) void k_prepw(
    const float* __restrict__ Wself, const float* __restrict__ Wneigh,
    unsigned short* __restrict__ W1T) {
  int c = blockIdx.x;
  int k = threadIdx.x;
  float v = (k < 128) ? Wself[(size_t)k * HID_F + c]
                      : Wneigh[(size_t)(k - 128) * HID_F + c];
  W1T[(size_t)c * 256 + k] = f2bf(v);
}

// ---------------------------------------------------------------------------
// K5: pull-gather, 4-edge-parallel (validated round 5)
// ---------------------------------------------------------------------------
__global__ __launch_bounds__(256) void k_gather(
    const int* __restrict__ offs, const unsigned* __restrict__ pairs,
    unsigned* __restrict__ A1u) {
  int node = blockIdx.x * 4 + (threadIdx.x >> 6);
  if (node >= N_NODES) return;
  const int lane = threadIdx.x & 63;
  const int g = lane >> 4;
  const int cl = lane & 15;
  const int start = offs[node], end = offs[node + 1];
  const int deg = end - start;

  float acc[8] = {0.f, 0.f, 0.f, 0.f, 0.f, 0.f, 0.f, 0.f};

  for (int k0 = start; k0 < end; k0 += 64) {
    unsigned pr = 0;
    if (k0 + lane < end) pr = pairs[k0 + lane];
    const int cnt = min(64, end - k0);
    const int nsteps = (cnt + 3) >> 2;
    for (int t = 0; t < nsteps; ++t) {
      unsigned uu = (unsigned)__shfl((int)pr, 4 * t + g, 64);
      int s = (int)(uu >> 15);
      float w = __half2float(__ushort_as_half((unsigned short)(uu & 0x7fffu)));
      uint4 f = *reinterpret_cast<const uint4*>(A1u + (size_t)s * 128 + cl * 4);
      acc[0] = fmaf(w, bf_lo(f.x), acc[0]);
      acc[1] = fmaf(w, bf_hi(f.x), acc[1]);
      acc[2] = fmaf(w, bf_lo(f.y), acc[2]);
      acc[3] = fmaf(w, bf_hi(f.y), acc[3]);
      acc[4] = fmaf(w, bf_lo(f.z), acc[4]);
      acc[5] = fmaf(w, bf_hi(f.z), acc[5]);
      acc[6] = fmaf(w, bf_lo(f.w), acc[6]);
      acc[7] = fmaf(w, bf_hi(f.w), acc[7]);
    }
  }

#pragma unroll
  for (int i = 0; i < 8; ++i) {
    acc[i] += __shfl_xor(acc[i], 16, 64);
    acc[i] += __shfl_xor(acc[i], 32, 64);
  }

  if (g == 0) {
    const float inv = (deg > 0) ? (1.0f / (float)deg) : 0.f;
    uint4 o;
    o.x = f2bf_pair(acc[0] * inv, acc[1] * inv);
    o.y = f2bf_pair(acc[2] * inv, acc[3] * inv);
    o.z = f2bf_pair(acc[4] * inv, acc[5] * inv);
    o.w = f2bf_pair(acc[6] * inv, acc[7] * inv);
    *reinterpret_cast<uint4*>(A1u + (size_t)node * 128 + 64 + cl * 4) = o;
  }
}

// ---------------------------------------------------------------------------
// K6: GEMM1, register-resident weights, persistent waves, grid-stride.
// 4 waves/block; wave w owns h-slice [w*64, w*64+64), full K=256 in regs
// (32 bf16x8 = 128 VGPR). Tile = 32 nodes; per ks: 2 node-row loads + 8 MFMA.
// BN stats accumulate in registers across tiles -> slab write at the end.
// ---------------------------------------------------------------------------
__global__ __launch_bounds__(256, 2) void k_gemm1(
    const unsigned short* __restrict__ A1, const unsigned short* __restrict__ W1T,
    const float* __restrict__ bias, unsigned short* __restrict__ y,
    float* __restrict__ colpart) {
  const int lane = threadIdx.x & 63;
  const int wid = threadIdx.x >> 6;
  const int l16 = lane & 15, lk = lane >> 4;
  const int h0 = wid * 64;

  // --- W slice -> registers (loaded once) ---
  bf16x8 wreg[8][4];
#pragma unroll
  for (int ks = 0; ks < 8; ++ks)
#pragma unroll
    for (int m = 0; m < 4; ++m)
      wreg[ks][m] = *reinterpret_cast<const bf16x8*>(
          W1T + (size_t)(h0 + m * 16 + l16) * 256 + ks * 32 + lk * 8);

  float4 bias4[4];
#pragma unroll
  for (int m = 0; m < 4; ++m)
    bias4[m] = *reinterpret_cast<const float4*>(bias + h0 + m * 16 + lk * 4);

  float sacc[4][4] = {};
  float qacc[4][4] = {};

  for (int t = blockIdx.x; t < NSUB; t += G1_GRID) {
    const int nbase = t * 32;
    f32x4 acc[4][2];
#pragma unroll
    for (int m = 0; m < 4; ++m)
#pragma unroll
      for (int n = 0; n < 2; ++n) acc[m][n] = (f32x4){0.f, 0.f, 0.f, 0.f};

#pragma unroll
    for (int ks = 0; ks < 8; ++ks) {
      bf16x8 bf0 = *reinterpret_cast<const bf16x8*>(
          A1 + (size_t)(nbase + l16) * 256 + ks * 32 + lk * 8);
      bf16x8 bf1 = *reinterpret_cast<const bf16x8*>(
          A1 + (size_t)(nbase + 16 + l16) * 256 + ks * 32 + lk * 8);
#pragma unroll
      for (int m = 0; m < 4; ++m) {
        acc[m][0] = __builtin_amdgcn_mfma_f32_16x16x32_bf16(
            wreg[ks][m], bf0, acc[m][0], 0, 0, 0);
        acc[m][1] = __builtin_amdgcn_mfma_f32_16x16x32_bf16(
            wreg[ks][m], bf1, acc[m][1], 0, 0, 0);
      }
    }

    // epilogue: bias + relu + packed bf16 store + stats accumulate
#pragma unroll
    for (int m = 0; m < 4; ++m) {
#pragma unroll
      for (int n = 0; n < 2; ++n) {
        float t0 = fmaxf(acc[m][n][0] + bias4[m].x, 0.f);
        float t1 = fmaxf(acc[m][n][1] + bias4[m].y, 0.f);
        float t2 = fmaxf(acc[m][n][2] + bias4[m].z, 0.f);
        float t3 = fmaxf(acc[m][n][3] + bias4[m].w, 0.f);
        uint2 pk;
        pk.x = f2bf_pair(t0, t1);
        pk.y = f2bf_pair(t2, t3);
        *reinterpret_cast<uint2*>(
            y + (size_t)(nbase + n * 16 + l16) * 256 + h0 + m * 16 + lk * 4) = pk;
        sacc[m][0] += t0; sacc[m][1] += t1; sacc[m][2] += t2; sacc[m][3] += t3;
        qacc[m][0] = fmaf(t0, t0, qacc[m][0]);
        qacc[m][1] = fmaf(t1, t1, qacc[m][1]);
        qacc[m][2] = fmaf(t2, t2, qacc[m][2]);
        qacc[m][3] = fmaf(t3, t3, qacc[m][3]);
      }
    }
  }

  // reduce stats across the 16 node-lanes; one slab row per block
#pragma unroll
  for (int m = 0; m < 4; ++m) {
#pragma unroll
    for (int r = 0; r < 4; ++r) {
      float s = sacc[m][r], q = qacc[m][r];
      s += __shfl_xor(s, 1, 64); s += __shfl_xor(s, 2, 64);
      s += __shfl_xor(s, 4, 64); s += __shfl_xor(s, 8, 64);
      q += __shfl_xor(q, 1, 64); q += __shfl_xor(q, 2, 64);
      q += __shfl_xor(q, 4, 64); q += __shfl_xor(q, 8, 64);
      if (l16 == 0) {
        int h = h0 + m * 16 + lk * 4 + r;
        colpart[(size_t)blockIdx.x * 512 + h] = s;
        colpart[(size_t)blockIdx.x * 512 + 256 + h] = q;
      }
    }
  }
}

// ---------------------------------------------------------------------------
// K6b: reduce colpart slab -> colsum/colsq (pre-zeroed)
// ---------------------------------------------------------------------------
__global__ __launch_bounds__(256) void k_redstats(
    const float* __restrict__ colpart, float* __restrict__ colsum,
    float* __restrict__ colsq) {
  const int h = threadIdx.x;
  float s = 0.f, q = 0.f;
  for (int j = blockIdx.x; j < G1_GRID; j += gridDim.x) {
    s += colpart[(size_t)j * 512 + h];
    q += colpart[(size_t)j * 512 + 256 + h];
  }
  atomicAdd(&colsum[h], s);
  atomicAdd(&colsq[h], q);
}

// ---------------------------------------------------------------------------
// K7: BN fold -> W2T[o][h] bf16 (o padded to 192), b2[o] f32
// ---------------------------------------------------------------------------
__global__ __launch_bounds__(256) void k_finalize(
    const float* __restrict__ colsum, const float* __restrict__ colsq,
    const float* __restrict__ gamma, const float* __restrict__ beta,
    const float* __restrict__ fcW, const float* __restrict__ fcb,
    unsigned short* __restrict__ W2T, float* __restrict__ b2) {
  const float invN = 1.0f / (float)N_NODES;
  if (blockIdx.x < 192) {
    int o = blockIdx.x, h = threadIdx.x;
    unsigned short v = 0;
    if (o < OUT_F) {
      float mu = colsum[h] * invN;
      float var = colsq[h] * invN - mu * mu;
      float rs = rsqrtf(var + BN_EPS) * gamma[h];
      v = f2bf(fcW[(size_t)h * OUT_F + o] * rs);
    }
    W2T[(size_t)o * 256 + h] = v;
  } else if (threadIdx.x < OUT_F) {
    int o = threadIdx.x;
    float acc = fcb[o];
    for (int h = 0; h < HID_F; ++h) {
      float mu = colsum[h] * invN;
      float var = colsq[h] * invN - mu * mu;
      float rs = rsqrtf(var + BN_EPS) * gamma[h];
      acc += (beta[h] - mu * rs) * fcW[(size_t)h * OUT_F + o];
    }
    b2[o] = acc;
  }
}

// ---------------------------------------------------------------------------
// K8: GEMM2, register-resident weights, persistent waves, grid-stride.
// 4 waves/block = 2 node-subtiles x 2 o-halves (80 o each, 5 m-frags).
// Tile = 64 nodes. Clamped loads + frag-guarded stores handle the tail.
// ---------------------------------------------------------------------------
__global__ __launch_bounds__(256, 2) void k_gemm2(
    const unsigned short* __restrict__ y, const unsigned short* __restrict__ W2T,
    const float* __restrict__ b2, float* __restrict__ out) {
  const int lane = threadIdx.x & 63;
  const int wid = threadIdx.x >> 6;
  const int l16 = lane & 15, lk = lane >> 4;
  const int wn = wid & 1;        // node subtile
  const int o0 = (wid >> 1) * 80;  // o half

  bf16x8 wreg[8][5];
#pragma unroll
  for (int ks = 0; ks < 8; ++ks)
#pragma unroll
    for (int m = 0; m < 5; ++m)
      wreg[ks][m] = *reinterpret_cast<const bf16x8*>(
          W2T + (size_t)(o0 + m * 16 + l16) * 256 + ks * 32 + lk * 8);

  float4 b24[5];
#pragma unroll
  for (int m = 0; m < 5; ++m)
    b24[m] = *reinterpret_cast<const float4*>(b2 + o0 + m * 16 + lk * 4);

  for (int t = blockIdx.x; t < NT2; t += G2_GRID) {
    const int nb = t * 64 + wn * 32;
    const int r0 = min(nb + l16, N_NODES - 1);
    const int r1 = min(nb + 16 + l16, N_NODES - 1);

    f32x4 acc[5][2];
#pragma unroll
    for (int m = 0; m < 5; ++m)
#pragma unroll
      for (int n = 0; n < 2; ++n) acc[m][n] = (f32x4){0.f, 0.f, 0.f, 0.f};

#pragma unroll
    for (int ks = 0; ks < 8; ++ks) {
      bf16x8 bf0 = *reinterpret_cast<const bf16x8*>(
          y + (size_t)r0 * 256 + ks * 32 + lk * 8);
      bf16x8 bf1 = *reinterpret_cast<const bf16x8*>(
          y + (size_t)r1 * 256 + ks * 32 + lk * 8);
#pragma unroll
      for (int m = 0; m < 5; ++m) {
        acc[m][0] = __builtin_amdgcn_mfma_f32_16x16x32_bf16(
            wreg[ks][m], bf0, acc[m][0], 0, 0, 0);
        acc[m][1] = __builtin_amdgcn_mfma_f32_16x16x32_bf16(
            wreg[ks][m], bf1, acc[m][1], 0, 0, 0);
      }
    }

#pragma unroll
    for (int n = 0; n < 2; ++n) {
      const int fb = nb + n * 16;
      if (fb < N_NODES) {   // N multiple of 16 -> frag fully valid
#pragma unroll
        for (int m = 0; m < 5; ++m) {
          float4 v;
          v.x = acc[m][n][0] + b24[m].x;
          v.y = acc[m][n][1] + b24[m].y;
          v.z = acc[m][n][2] + b24[m].z;
          v.w = acc[m][n][3] + b24[m].w;
          *reinterpret_cast<float4*>(
              out + (size_t)(fb + l16) * OUT_F + o0 + m * 16 + lk * 4) = v;
        }
      }
    }
  }
}

// ---------------------------------------------------------------------------
extern "C" void kernel_launch(void* const* d_in, const int* in_sizes, int n_in,
                              void* d_out, int out_size, void* d_ws,
                              size_t ws_size, hipStream_t stream) {
  const float* feat   = (const float*)d_in[0];
  const int*   src    = (const int*)d_in[1];
  const int*   dst    = (const int*)d_in[2];
  const float* ew     = (const float*)d_in[3];
  const float* Wself  = (const float*)d_in[4];
  const float* Wneigh = (const float*)d_in[5];
  const float* bias   = (const float*)d_in[6];
  const float* gamma  = (const float*)d_in[7];
  const float* beta   = (const float*)d_in[8];
  const float* fcW    = (const float*)d_in[9];
  const float* fcb    = (const float*)d_in[10];
  float* out = (float*)d_out;

  char* ws = (char*)d_ws;
  // layout (bytes):
  //   [0,        400,000)   cursor  N i32            (zeroed)
  //   [400,000,  401,024)   colsum  256 f32          (zeroed)
  //   [401,024,  402,048)   colsq   256 f32          (zeroed)
  //   [402,048,  802,052)   offs    (N+1) i32
  //   [802,304,  802,696)   totals  98 i32
  //   [802,816,  803,208)   bases   98 i32
  //   [803,328,  7,203,328) pairs   E u32
  //   [7,203,328, 58,403,328)  A1      N*256 bf16 (feat | neigh)
  //   [58,403,328,58,534,400)  W1T     256*256 bf16
  //   [58,534,400,58,632,704)  W2T     192*256 bf16
  //   [58,632,704,58,633,344)  b2      160 f32
  //   [58,633,344,109,833,344) y       N*256 bf16
  //   [109,833,344,110,881,920) colpart 512*512 f32
  int*            cursor  = (int*)(ws + 0);
  float*          colsum  = (float*)(ws + 400000);
  float*          colsq   = (float*)(ws + 401024);
  int*            offs    = (int*)(ws + 402048);
  int*            totals  = (int*)(ws + 802304);
  int*            bases   = (int*)(ws + 802816);
  unsigned*       pairs   = (unsigned*)(ws + 803328);
  unsigned*       A1u     = (unsigned*)(ws + 7203328);
  unsigned short* A1      = (unsigned short*)(ws + 7203328);
  unsigned short* W1T     = (unsigned short*)(ws + 58403328);
  unsigned short* W2T     = (unsigned short*)(ws + 58534400);
  float*          b2      = (float*)(ws + 58632704);
  unsigned short* y       = (unsigned short*)(ws + 58633344);
  float*          colpart = (float*)(ws + 109833344);

  hipMemsetAsync(ws, 0, 402048, stream);

  dim3 b256(256);
  k_convert<<<dim3((N_NODES * IN_F / 8 + 255) / 256), b256, 0, stream>>>(
      feat, A1u);
  k_prepw<<<dim3(256), b256, 0, stream>>>(Wself, Wneigh, W1T);
  k_hist<<<dim3(NCHUNK * 8), b256, 0, stream>>>(dst, cursor);
  k_scan1<<<dim3(SCHUNK), dim3(1024), 0, stream>>>(cursor, offs, totals);
  k_scan2<<<dim3(1), dim3(128), 0, stream>>>(totals, bases);
  k_scan3<<<dim3((N_NODES + 255) / 256), b256, 0, stream>>>(
      offs, cursor, bases);
  k_place<<<dim3(NCHUNK * 8), b256, 0, stream>>>(
      src, dst, ew, cursor, pairs);
  k_gather<<<dim3((N_NODES + 3) / 4), b256, 0, stream>>>(offs, pairs, A1u);
  k_gemm1<<<dim3(G1_GRID), b256, 0, stream>>>(A1, W1T, bias, y, colpart);
  k_redstats<<<dim3(32), b256, 0, stream>>>(colpart, colsum, colsq);
  k_finalize<<<dim3(193), b256, 0, stream>>>(
      colsum, colsq, gamma, beta, fcW, fcb, W2T, b2);
  k_gemm2<<<dim3(G2_GRID), b256, 0, stream>>>(y, W2T, b2, out);
}

// Round 9
// 293.496 us; speedup vs baseline: 1.3776x; 1.1348x over previous
//
#include <hip/hip_runtime.h>
#include <hip/hip_fp16.h>

#define N_NODES 100000
#define N_EDGES 1600000
#define IN_F    128
#define HID_F   256
#define OUT_F   160
#define BN_EPS  1e-5f

#define EPB     4096                         // edges per bucket-block
#define NCHUNK  ((N_EDGES + EPB - 1) / EPB)  // 391
#define NPP     (N_NODES / 8)                // 12500 nodes per XCD partition
#define SCHUNK  ((N_NODES + 1023) / 1024)    // 98 scan chunks
#define NSUB    (N_NODES / 32)               // 3125 32-node tiles (exact)
#define G1_GRID 512
#define NT2     ((N_NODES + 63) / 64)        // 1563 64-node tiles
#define G2_GRID 512
#define BCAP    262144                       // bucket capacity (avg 200k, +134 sigma)
#define HB_PER_P 48                          // hist2/place2 blocks per partition

typedef __attribute__((ext_vector_type(8))) short bf16x8;
typedef __attribute__((ext_vector_type(4))) float f32x4;

static __device__ inline unsigned short f2bf(float x) {
  unsigned u = __float_as_uint(x);
  return (unsigned short)((u + 0x7fffu + ((u >> 16) & 1u)) >> 16);
}
static __device__ inline unsigned f2bf_pair(float lo, float hi) {
  return (unsigned)f2bf(lo) | ((unsigned)f2bf(hi) << 16);
}
static __device__ inline float bf_lo(unsigned u) {
  return __uint_as_float(u << 16);
}
static __device__ inline float bf_hi(unsigned u) {
  return __uint_as_float(u & 0xffff0000u);
}

// ---------------------------------------------------------------------------
// K0: single-pass bucket scatter. Block stages 4096 edges in regs, LDS-hists
// into 8 XCD partitions, reserves global space (1 atomic/bucket/block), then
// scatters (dst, src<<15|fp16w) uint2 into dense per-partition arrays.
// ---------------------------------------------------------------------------
__global__ __launch_bounds__(256) void k_bucket(
    const int* __restrict__ src, const int* __restrict__ dst,
    const float* __restrict__ ew, int* __restrict__ gcnt,
    uint2* __restrict__ bucket) {
  __shared__ int bcnt[8];
  __shared__ int bcur[8];
  const int tid = threadIdx.x;
  const int e0 = blockIdx.x * EPB;
  if (tid < 8) bcnt[tid] = 0;
  __syncthreads();
  int ed[16];
  unsigned pd[16];
#pragma unroll
  for (int i = 0; i < 16; ++i) {
    int e = e0 + i * 256 + tid;
    int d = -1;
    unsigned p = 0;
    if (e < N_EDGES) {
      d = dst[e];
      unsigned hb = (unsigned)__half_as_ushort(__float2half(ew[e])) & 0x7fffu;
      p = ((unsigned)src[e] << 15) | hb;
      atomicAdd(&bcnt[d / NPP], 1);
    }
    ed[i] = d;
    pd[i] = p;
  }
  __syncthreads();
  if (tid < 8) bcur[tid] = atomicAdd(&gcnt[tid], bcnt[tid]);
  __syncthreads();
#pragma unroll
  for (int i = 0; i < 16; ++i) {
    if (ed[i] >= 0) {
      int b = ed[i] / NPP;
      int pos = atomicAdd(&bcur[b], 1);
      if (pos < BCAP)
        bucket[(size_t)b * BCAP + pos] = make_uint2((unsigned)ed[i], pd[i]);
    }
  }
}

// ---------------------------------------------------------------------------
// K0b: dense partition-local histogram + per-edge rank.
// Block group p works only on bucket p (XCD-local cursor slice).
// ---------------------------------------------------------------------------
__global__ __launch_bounds__(256) void k_hist2(
    const uint2* __restrict__ bucket, const int* __restrict__ gcnt,
    int* __restrict__ cursor, int* __restrict__ rank) {
  const int p = blockIdx.x & 7;
  const int chunk = blockIdx.x >> 3;
  const int n = min(gcnt[p], BCAP);
  const uint2* bp = bucket + (size_t)p * BCAP;
  int* rp = rank + (size_t)p * BCAP;
  for (int i = chunk * 256 + threadIdx.x; i < n; i += HB_PER_P * 256) {
    int d = (int)bp[i].x;
    rp[i] = atomicAdd(&cursor[d], 1);
  }
}

// ---------------------------------------------------------------------------
// K1a: per-chunk scan (98 blocks x 1024)
// ---------------------------------------------------------------------------
__global__ __launch_bounds__(1024) void k_scan1(const int* __restrict__ cursor,
                                                int* __restrict__ offs,
                                                int* __restrict__ totals) {
  __shared__ int wsum[16];
  __shared__ int ctot;
  const int tid = threadIdx.x, lane = tid & 63, wid = tid >> 6;
  int i = blockIdx.x * 1024 + tid;
  int v = (i < N_NODES) ? cursor[i] : 0;
  int x = v;
#pragma unroll
  for (int off = 1; off < 64; off <<= 1) {
    int t = __shfl_up(x, off, 64);
    if (lane >= off) x += t;
  }
  if (lane == 63) wsum[wid] = x;
  __syncthreads();
  if (wid == 0) {
    int s = (lane < 16) ? wsum[lane] : 0;
    int y = s;
#pragma unroll
    for (int off = 1; off < 16; off <<= 1) {
      int t = __shfl_up(y, off, 64);
      if (lane >= off) y += t;
    }
    if (lane < 16) wsum[lane] = y - s;
    if (lane == 15) ctot = y;
  }
  __syncthreads();
  if (i < N_NODES) offs[i] = wsum[wid] + (x - v);
  if (tid == 0) totals[blockIdx.x] = ctot;
}

// ---------------------------------------------------------------------------
// K1b: scan 98 chunk totals -> bases
// ---------------------------------------------------------------------------
__global__ __launch_bounds__(128) void k_scan2(const int* __restrict__ totals,
                                               int* __restrict__ bases) {
  __shared__ int w0t;
  const int tid = threadIdx.x, lane = tid & 63;
  int t = (tid < SCHUNK) ? totals[tid] : 0;
  int x = t;
#pragma unroll
  for (int off = 1; off < 64; off <<= 1) {
    int q = __shfl_up(x, off, 64);
    if (lane >= off) x += q;
  }
  if (tid == 63) w0t = x;
  __syncthreads();
  int excl = x - t + ((tid >= 64) ? w0t : 0);
  if (tid < SCHUNK) bases[tid] = excl;
}

// ---------------------------------------------------------------------------
// K1c: add bases -> final exclusive offsets
// ---------------------------------------------------------------------------
__global__ __launch_bounds__(256) void k_scan3(int* __restrict__ offs,
                                               const int* __restrict__ bases) {
  int i = blockIdx.x * 256 + threadIdx.x;
  if (i < N_NODES) offs[i] += bases[i >> 10];
  if (i == 0) offs[N_NODES] = N_EDGES;
}

// ---------------------------------------------------------------------------
// K2: atomic-free place: pairs[offs[d] + rank[i]] = pdata
// ---------------------------------------------------------------------------
__global__ __launch_bounds__(256) void k_place2(
    const uint2* __restrict__ bucket, const int* __restrict__ gcnt,
    const int* __restrict__ rank, const int* __restrict__ offs,
    unsigned* __restrict__ pairs) {
  const int p = blockIdx.x & 7;
  const int chunk = blockIdx.x >> 3;
  const int n = min(gcnt[p], BCAP);
  const uint2* bp = bucket + (size_t)p * BCAP;
  const int* rp = rank + (size_t)p * BCAP;
  for (int i = chunk * 256 + threadIdx.x; i < n; i += HB_PER_P * 256) {
    uint2 it = bp[i];
    pairs[offs[it.x] + rp[i]] = it.y;
  }
}

// ---------------------------------------------------------------------------
// K3: feat fp32 -> bf16 into A1 columns 0..127 (row stride 256 bf16)
// ---------------------------------------------------------------------------
__global__ __launch_bounds__(256) void k_convert(
    const float* __restrict__ feat, unsigned* __restrict__ A1u) {
  long long idx = (long long)blockIdx.x * 256 + threadIdx.x;
  long long fidx = idx * 8;
  if (fidx >= (long long)N_NODES * IN_F) return;
  int node = (int)(fidx >> 7);
  int c0 = (int)(fidx & 127);
  float4 f0 = *reinterpret_cast<const float4*>(feat + fidx);
  float4 f1 = *reinterpret_cast<const float4*>(feat + fidx + 4);
  uint4 o;
  o.x = f2bf_pair(f0.x, f0.y);
  o.y = f2bf_pair(f0.z, f0.w);
  o.z = f2bf_pair(f1.x, f1.y);
  o.w = f2bf_pair(f1.z, f1.w);
  *reinterpret_cast<uint4*>(A1u + (size_t)node * 128 + (c0 >> 1)) = o;
}

// ---------------------------------------------------------------------------
// K4: W1T[c][k] = bf16( k<128 ? Wself[k][c] : Wneigh[k-128][c] )
// ---------------------------------------------------------------------------
__global__ __launch_bounds__(256) void k_prepw(
    const float* __restrict__ Wself, const float* __restrict__ Wneigh,
    unsigned short* __restrict__ W1T) {
  int c = blockIdx.x;
  int k = threadIdx.x;
  float v = (k < 128) ? Wself[(size_t)k * HID_F + c]
                      : Wneigh[(size_t)(k - 128) * HID_F + c];
  W1T[(size_t)c * 256 + k] = f2bf(v);
}

// ---------------------------------------------------------------------------
// K5: pull-gather, 4-edge-parallel (validated round 5)
// ---------------------------------------------------------------------------
__global__ __launch_bounds__(256) void k_gather(
    const int* __restrict__ offs, const unsigned* __restrict__ pairs,
    unsigned* __restrict__ A1u) {
  int node = blockIdx.x * 4 + (threadIdx.x >> 6);
  if (node >= N_NODES) return;
  const int lane = threadIdx.x & 63;
  const int g = lane >> 4;
  const int cl = lane & 15;
  const int start = offs[node], end = offs[node + 1];
  const int deg = end - start;

  float acc[8] = {0.f, 0.f, 0.f, 0.f, 0.f, 0.f, 0.f, 0.f};

  for (int k0 = start; k0 < end; k0 += 64) {
    unsigned pr = 0;
    if (k0 + lane < end) pr = pairs[k0 + lane];
    const int cnt = min(64, end - k0);
    const int nsteps = (cnt + 3) >> 2;
    for (int t = 0; t < nsteps; ++t) {
      unsigned uu = (unsigned)__shfl((int)pr, 4 * t + g, 64);
      int s = (int)(uu >> 15);
      float w = __half2float(__ushort_as_half((unsigned short)(uu & 0x7fffu)));
      uint4 f = *reinterpret_cast<const uint4*>(A1u + (size_t)s * 128 + cl * 4);
      acc[0] = fmaf(w, bf_lo(f.x), acc[0]);
      acc[1] = fmaf(w, bf_hi(f.x), acc[1]);
      acc[2] = fmaf(w, bf_lo(f.y), acc[2]);
      acc[3] = fmaf(w, bf_hi(f.y), acc[3]);
      acc[4] = fmaf(w, bf_lo(f.z), acc[4]);
      acc[5] = fmaf(w, bf_hi(f.z), acc[5]);
      acc[6] = fmaf(w, bf_lo(f.w), acc[6]);
      acc[7] = fmaf(w, bf_hi(f.w), acc[7]);
    }
  }

#pragma unroll
  for (int i = 0; i < 8; ++i) {
    acc[i] += __shfl_xor(acc[i], 16, 64);
    acc[i] += __shfl_xor(acc[i], 32, 64);
  }

  if (g == 0) {
    const float inv = (deg > 0) ? (1.0f / (float)deg) : 0.f;
    uint4 o;
    o.x = f2bf_pair(acc[0] * inv, acc[1] * inv);
    o.y = f2bf_pair(acc[2] * inv, acc[3] * inv);
    o.z = f2bf_pair(acc[4] * inv, acc[5] * inv);
    o.w = f2bf_pair(acc[6] * inv, acc[7] * inv);
    *reinterpret_cast<uint4*>(A1u + (size_t)node * 128 + 64 + cl * 4) = o;
  }
}

// ---------------------------------------------------------------------------
// K6: GEMM1, register-resident weights, persistent waves (validated round 8)
// ---------------------------------------------------------------------------
__global__ __launch_bounds__(256, 2) void k_gemm1(
    const unsigned short* __restrict__ A1, const unsigned short* __restrict__ W1T,
    const float* __restrict__ bias, unsigned short* __restrict__ y,
    float* __restrict__ colpart) {
  const int lane = threadIdx.x & 63;
  const int wid = threadIdx.x >> 6;
  const int l16 = lane & 15, lk = lane >> 4;
  const int h0 = wid * 64;

  bf16x8 wreg[8][4];
#pragma unroll
  for (int ks = 0; ks < 8; ++ks)
#pragma unroll
    for (int m = 0; m < 4; ++m)
      wreg[ks][m] = *reinterpret_cast<const bf16x8*>(
          W1T + (size_t)(h0 + m * 16 + l16) * 256 + ks * 32 + lk * 8);

  float4 bias4[4];
#pragma unroll
  for (int m = 0; m < 4; ++m)
    bias4[m] = *reinterpret_cast<const float4*>(bias + h0 + m * 16 + lk * 4);

  float sacc[4][4] = {};
  float qacc[4][4] = {};

  for (int t = blockIdx.x; t < NSUB; t += G1_GRID) {
    const int nbase = t * 32;
    f32x4 acc[4][2];
#pragma unroll
    for (int m = 0; m < 4; ++m)
#pragma unroll
      for (int n = 0; n < 2; ++n) acc[m][n] = (f32x4){0.f, 0.f, 0.f, 0.f};

#pragma unroll
    for (int ks = 0; ks < 8; ++ks) {
      bf16x8 bf0 = *reinterpret_cast<const bf16x8*>(
          A1 + (size_t)(nbase + l16) * 256 + ks * 32 + lk * 8);
      bf16x8 bf1 = *reinterpret_cast<const bf16x8*>(
          A1 + (size_t)(nbase + 16 + l16) * 256 + ks * 32 + lk * 8);
#pragma unroll
      for (int m = 0; m < 4; ++m) {
        acc[m][0] = __builtin_amdgcn_mfma_f32_16x16x32_bf16(
            wreg[ks][m], bf0, acc[m][0], 0, 0, 0);
        acc[m][1] = __builtin_amdgcn_mfma_f32_16x16x32_bf16(
            wreg[ks][m], bf1, acc[m][1], 0, 0, 0);
      }
    }

#pragma unroll
    for (int m = 0; m < 4; ++m) {
#pragma unroll
      for (int n = 0; n < 2; ++n) {
        float t0 = fmaxf(acc[m][n][0] + bias4[m].x, 0.f);
        float t1 = fmaxf(acc[m][n][1] + bias4[m].y, 0.f);
        float t2 = fmaxf(acc[m][n][2] + bias4[m].z, 0.f);
        float t3 = fmaxf(acc[m][n][3] + bias4[m].w, 0.f);
        uint2 pk;
        pk.x = f2bf_pair(t0, t1);
        pk.y = f2bf_pair(t2, t3);
        *reinterpret_cast<uint2*>(
            y + (size_t)(nbase + n * 16 + l16) * 256 + h0 + m * 16 + lk * 4) = pk;
        sacc[m][0] += t0; sacc[m][1] += t1; sacc[m][2] += t2; sacc[m][3] += t3;
        qacc[m][0] = fmaf(t0, t0, qacc[m][0]);
        qacc[m][1] = fmaf(t1, t1, qacc[m][1]);
        qacc[m][2] = fmaf(t2, t2, qacc[m][2]);
        qacc[m][3] = fmaf(t3, t3, qacc[m][3]);
      }
    }
  }

#pragma unroll
  for (int m = 0; m < 4; ++m) {
#pragma unroll
    for (int r = 0; r < 4; ++r) {
      float s = sacc[m][r], q = qacc[m][r];
      s += __shfl_xor(s, 1, 64); s += __shfl_xor(s, 2, 64);
      s += __shfl_xor(s, 4, 64); s += __shfl_xor(s, 8, 64);
      q += __shfl_xor(q, 1, 64); q += __shfl_xor(q, 2, 64);
      q += __shfl_xor(q, 4, 64); q += __shfl_xor(q, 8, 64);
      if (l16 == 0) {
        int h = h0 + m * 16 + lk * 4 + r;
        colpart[(size_t)blockIdx.x * 512 + h] = s;
        colpart[(size_t)blockIdx.x * 512 + 256 + h] = q;
      }
    }
  }
}

// ---------------------------------------------------------------------------
// K6b: reduce colpart slab -> colsum/colsq (pre-zeroed)
// ---------------------------------------------------------------------------
__global__ __launch_bounds__(256) void k_redstats(
    const float* __restrict__ colpart, float* __restrict__ colsum,
    float* __restrict__ colsq) {
  const int h = threadIdx.x;
  float s = 0.f, q = 0.f;
  for (int j = blockIdx.x; j < G1_GRID; j += gridDim.x) {
    s += colpart[(size_t)j * 512 + h];
    q += colpart[(size_t)j * 512 + 256 + h];
  }
  atomicAdd(&colsum[h], s);
  atomicAdd(&colsq[h], q);
}

// ---------------------------------------------------------------------------
// K7: BN fold -> W2T[o][h] bf16 (o padded to 192), b2[o] f32
// ---------------------------------------------------------------------------
__global__ __launch_bounds__(256) void k_finalize(
    const float* __restrict__ colsum, const float* __restrict__ colsq,
    const float* __restrict__ gamma, const float* __restrict__ beta,
    const float* __restrict__ fcW, const float* __restrict__ fcb,
    unsigned short* __restrict__ W2T, float* __restrict__ b2) {
  const float invN = 1.0f / (float)N_NODES;
  if (blockIdx.x < 192) {
    int o = blockIdx.x, h = threadIdx.x;
    unsigned short v = 0;
    if (o < OUT_F) {
      float mu = colsum[h] * invN;
      float var = colsq[h] * invN - mu * mu;
      float rs = rsqrtf(var + BN_EPS) * gamma[h];
      v = f2bf(fcW[(size_t)h * OUT_F + o] * rs);
    }
    W2T[(size_t)o * 256 + h] = v;
  } else if (threadIdx.x < OUT_F) {
    int o = threadIdx.x;
    float acc = fcb[o];
    for (int h = 0; h < HID_F; ++h) {
      float mu = colsum[h] * invN;
      float var = colsq[h] * invN - mu * mu;
      float rs = rsqrtf(var + BN_EPS) * gamma[h];
      acc += (beta[h] - mu * rs) * fcW[(size_t)h * OUT_F + o];
    }
    b2[o] = acc;
  }
}

// ---------------------------------------------------------------------------
// K8: GEMM2, register-resident weights, persistent waves (validated round 8)
// ---------------------------------------------------------------------------
__global__ __launch_bounds__(256, 2) void k_gemm2(
    const unsigned short* __restrict__ y, const unsigned short* __restrict__ W2T,
    const float* __restrict__ b2, float* __restrict__ out) {
  const int lane = threadIdx.x & 63;
  const int wid = threadIdx.x >> 6;
  const int l16 = lane & 15, lk = lane >> 4;
  const int wn = wid & 1;
  const int o0 = (wid >> 1) * 80;

  bf16x8 wreg[8][5];
#pragma unroll
  for (int ks = 0; ks < 8; ++ks)
#pragma unroll
    for (int m = 0; m < 5; ++m)
      wreg[ks][m] = *reinterpret_cast<const bf16x8*>(
          W2T + (size_t)(o0 + m * 16 + l16) * 256 + ks * 32 + lk * 8);

  float4 b24[5];
#pragma unroll
  for (int m = 0; m < 5; ++m)
    b24[m] = *reinterpret_cast<const float4*>(b2 + o0 + m * 16 + lk * 4);

  for (int t = blockIdx.x; t < NT2; t += G2_GRID) {
    const int nb = t * 64 + wn * 32;
    const int r0 = min(nb + l16, N_NODES - 1);
    const int r1 = min(nb + 16 + l16, N_NODES - 1);

    f32x4 acc[5][2];
#pragma unroll
    for (int m = 0; m < 5; ++m)
#pragma unroll
      for (int n = 0; n < 2; ++n) acc[m][n] = (f32x4){0.f, 0.f, 0.f, 0.f};

#pragma unroll
    for (int ks = 0; ks < 8; ++ks) {
      bf16x8 bf0 = *reinterpret_cast<const bf16x8*>(
          y + (size_t)r0 * 256 + ks * 32 + lk * 8);
      bf16x8 bf1 = *reinterpret_cast<const bf16x8*>(
          y + (size_t)r1 * 256 + ks * 32 + lk * 8);
#pragma unroll
      for (int m = 0; m < 5; ++m) {
        acc[m][0] = __builtin_amdgcn_mfma_f32_16x16x32_bf16(
            wreg[ks][m], bf0, acc[m][0], 0, 0, 0);
        acc[m][1] = __builtin_amdgcn_mfma_f32_16x16x32_bf16(
            wreg[ks][m], bf1, acc[m][1], 0, 0, 0);
      }
    }

#pragma unroll
    for (int n = 0; n < 2; ++n) {
      const int fb = nb + n * 16;
      if (fb < N_NODES) {
#pragma unroll
        for (int m = 0; m < 5; ++m) {
          float4 v;
          v.x = acc[m][n][0] + b24[m].x;
          v.y = acc[m][n][1] + b24[m].y;
          v.z = acc[m][n][2] + b24[m].z;
          v.w = acc[m][n][3] + b24[m].w;
          *reinterpret_cast<float4*>(
              out + (size_t)(fb + l16) * OUT_F + o0 + m * 16 + lk * 4) = v;
        }
      }
    }
  }
}

// ---------------------------------------------------------------------------
extern "C" void kernel_launch(void* const* d_in, const int* in_sizes, int n_in,
                              void* d_out, int out_size, void* d_ws,
                              size_t ws_size, hipStream_t stream) {
  const float* feat   = (const float*)d_in[0];
  const int*   src    = (const int*)d_in[1];
  const int*   dst    = (const int*)d_in[2];
  const float* ew     = (const float*)d_in[3];
  const float* Wself  = (const float*)d_in[4];
  const float* Wneigh = (const float*)d_in[5];
  const float* bias   = (const float*)d_in[6];
  const float* gamma  = (const float*)d_in[7];
  const float* beta   = (const float*)d_in[8];
  const float* fcW    = (const float*)d_in[9];
  const float* fcb    = (const float*)d_in[10];
  float* out = (float*)d_out;

  char* ws = (char*)d_ws;
  // layout (bytes):
  //   [0,        400,000)    cursor  N i32           (zeroed)
  //   [400,000,  401,024)    colsum  256 f32         (zeroed)
  //   [401,024,  402,048)    colsq   256 f32         (zeroed)
  //   [402,048,  402,080)    gcnt    8 i32           (zeroed)
  //   [402,176,  802,180)    offs    (N+1) i32
  //   [802,304,  802,696)    totals  98 i32
  //   [802,816,  803,208)    bases   98 i32
  //   [803,328,  9,191,936)  rank    8*BCAP i32
  //   [9,191,936, 15,591,936) pairs  E u32
  //   [15,591,936, 32,369,152) bucket 8*BCAP uint2
  //   [32,369,152, 83,569,152) A1    N*256 bf16 (feat | neigh)
  //   [83,569,152, 83,700,224) W1T   256*256 bf16
  //   [83,700,224, 83,798,528) W2T   192*256 bf16
  //   [83,798,528, 83,799,168) b2    160 f32
  //   [83,799,168, 134,999,168) y    N*256 bf16
  //   [134,999,168, 136,047,744) colpart 512*512 f32
  int*            cursor  = (int*)(ws + 0);
  float*          colsum  = (float*)(ws + 400000);
  float*          colsq   = (float*)(ws + 401024);
  int*            gcnt    = (int*)(ws + 402048);
  int*            offs    = (int*)(ws + 402176);
  int*            totals  = (int*)(ws + 802304);
  int*            bases   = (int*)(ws + 802816);
  int*            rank    = (int*)(ws + 803328);
  unsigned*       pairs   = (unsigned*)(ws + 9191936);
  uint2*          bucket  = (uint2*)(ws + 15591936);
  unsigned*       A1u     = (unsigned*)(ws + 32369152);
  unsigned short* A1      = (unsigned short*)(ws + 32369152);
  unsigned short* W1T     = (unsigned short*)(ws + 83569152);
  unsigned short* W2T     = (unsigned short*)(ws + 83700224);
  float*          b2      = (float*)(ws + 83798528);
  unsigned short* y       = (unsigned short*)(ws + 83799168);
  float*          colpart = (float*)(ws + 134999168);

  hipMemsetAsync(ws, 0, 402080, stream);

  dim3 b256(256);
  k_convert<<<dim3((N_NODES * IN_F / 8 + 255) / 256), b256, 0, stream>>>(
      feat, A1u);
  k_prepw<<<dim3(256), b256, 0, stream>>>(Wself, Wneigh, W1T);
  k_bucket<<<dim3(NCHUNK), b256, 0, stream>>>(src, dst, ew, gcnt, bucket);
  k_hist2<<<dim3(HB_PER_P * 8), b256, 0, stream>>>(bucket, gcnt, cursor, rank);
  k_scan1<<<dim3(SCHUNK), dim3(1024), 0, stream>>>(cursor, offs, totals);
  k_scan2<<<dim3(1), dim3(128), 0, stream>>>(totals, bases);
  k_scan3<<<dim3((N_NODES + 255) / 256), b256, 0, stream>>>(offs, bases);
  k_place2<<<dim3(HB_PER_P * 8), b256, 0, stream>>>(
      bucket, gcnt, rank, offs, pairs);
  k_gather<<<dim3((N_NODES + 3) / 4), b256, 0, stream>>>(offs, pairs, A1u);
  k_gemm1<<<dim3(G1_GRID), b256, 0, stream>>>(A1, W1T, bias, y, colpart);
  k_redstats<<<dim3(32), b256, 0, stream>>>(colpart, colsum, colsq);
  k_finalize<<<dim3(193), b256, 0, stream>>>(
      colsum, colsq, gamma, beta, fcW, fcb, W2T, b2);
  k_gemm2<<<dim3(G2_GRID), b256, 0, stream>>>(y, W2T, b2, out);
}

// Round 10
// 227.792 us; speedup vs baseline: 1.7750x; 1.2884x over previous
//
#include <hip/hip_runtime.h>
#include <hip/hip_fp16.h>

#define N_NODES 100000
#define N_EDGES 1600000
#define IN_F    128
#define HID_F   256
#define OUT_F   160
#define BN_EPS  1e-5f

#define EPB     4096                         // edges per bucket-block
#define NCHUNK  ((N_EDGES + EPB - 1) / EPB)  // 391
#define NBKT    256                          // buckets (node ranges)
#define NPP2    391                          // nodes per bucket (256*391 >= N)
#define BCAP2   8192                         // bucket capacity (mean 6250, +24 sigma)
#define NSUB    (N_NODES / 32)               // 3125 32-node tiles (exact)
#define G1_GRID 512
#define NT2     ((N_NODES + 63) / 64)        // 1563 64-node tiles
#define G2_GRID 512

typedef __attribute__((ext_vector_type(8))) short bf16x8;
typedef __attribute__((ext_vector_type(4))) float f32x4;

static __device__ inline unsigned short f2bf(float x) {
  unsigned u = __float_as_uint(x);
  return (unsigned short)((u + 0x7fffu + ((u >> 16) & 1u)) >> 16);
}
static __device__ inline unsigned f2bf_pair(float lo, float hi) {
  return (unsigned)f2bf(lo) | ((unsigned)f2bf(hi) << 16);
}
static __device__ inline float bf_lo(unsigned u) {
  return __uint_as_float(u << 16);
}
static __device__ inline float bf_hi(unsigned u) {
  return __uint_as_float(u & 0xffff0000u);
}

// ---------------------------------------------------------------------------
// K0: single-pass 256-way bucket scatter. Block stages 4096 edges in regs,
// LDS-hists into 256 node-range buckets, reserves global space (1 atomic per
// bucket per block), scatters (dst, src<<15|fp16w) uint2 into dense buckets.
// ---------------------------------------------------------------------------
__global__ __launch_bounds__(256) void k_bucket(
    const int* __restrict__ src, const int* __restrict__ dst,
    const float* __restrict__ ew, int* __restrict__ gcnt,
    uint2* __restrict__ bucket) {
  __shared__ int bcnt[NBKT];
  __shared__ int bcur[NBKT];
  const int tid = threadIdx.x;
  const int e0 = blockIdx.x * EPB;
  bcnt[tid] = 0;
  __syncthreads();
  int ed[16];
  unsigned pd[16];
#pragma unroll
  for (int i = 0; i < 16; ++i) {
    int e = e0 + i * 256 + tid;
    int d = -1;
    unsigned p = 0;
    if (e < N_EDGES) {
      d = dst[e];
      unsigned hb = (unsigned)__half_as_ushort(__float2half(ew[e])) & 0x7fffu;
      p = ((unsigned)src[e] << 15) | hb;
      atomicAdd(&bcnt[d / NPP2], 1);
    }
    ed[i] = d;
    pd[i] = p;
  }
  __syncthreads();
  bcur[tid] = atomicAdd(&gcnt[tid], bcnt[tid]);
  __syncthreads();
#pragma unroll
  for (int i = 0; i < 16; ++i) {
    if (ed[i] >= 0) {
      int b = ed[i] / NPP2;
      int pos = atomicAdd(&bcur[b], 1);
      if (pos < BCAP2)
        bucket[(size_t)b * BCAP2 + pos] = make_uint2((unsigned)ed[i], pd[i]);
    }
  }
}

// ---------------------------------------------------------------------------
// K0b: scan 256 bucket totals -> bbase (1 block, 256 threads = 4 waves)
// ---------------------------------------------------------------------------
__global__ __launch_bounds__(256) void k_scanb(const int* __restrict__ gcnt,
                                               int* __restrict__ bbase,
                                               int* __restrict__ offs) {
  __shared__ int wsum[4];
  const int tid = threadIdx.x, lane = tid & 63, wid = tid >> 6;
  int t = gcnt[tid];
  int x = t;
#pragma unroll
  for (int off = 1; off < 64; off <<= 1) {
    int q = __shfl_up(x, off, 64);
    if (lane >= off) x += q;
  }
  if (lane == 63) wsum[wid] = x;
  __syncthreads();
  int pre = 0;
#pragma unroll
  for (int w = 0; w < 4; ++w)
    if (w < wid) pre += wsum[w];
  int excl = pre + x - t;
  bbase[tid] = excl;
  if (tid == 255) bbase[256] = excl + t;
  if (tid == 0) offs[N_NODES] = N_EDGES;
}

// ---------------------------------------------------------------------------
// K0c: per-bucket LDS counting sort -> offs + pairs. One block per bucket;
// all per-edge atomics are LDS (391 counters). No global atomics.
// ---------------------------------------------------------------------------
__global__ __launch_bounds__(256) void k_csr(
    const uint2* __restrict__ bucket, const int* __restrict__ gcnt,
    const int* __restrict__ bbase, int* __restrict__ offs,
    unsigned* __restrict__ pairs) {
  __shared__ int cnt[512];
  const int b = blockIdx.x;
  const int tid = threadIdx.x;
  const int lo = b * NPP2;
  const int n = min(gcnt[b], BCAP2);
  const uint2* bp = bucket + (size_t)b * BCAP2;

  cnt[tid] = 0;
  cnt[tid + 256] = 0;
  __syncthreads();

  // pass 1: LDS histogram
  for (int i = tid; i < n; i += 256)
    atomicAdd(&cnt[(int)bp[i].x - lo], 1);
  __syncthreads();

  // exclusive scan over 512 counters (wave 0, 8 shfl-chunks with carry)
  if (tid < 64) {
    int carry = 0;
#pragma unroll
    for (int c = 0; c < 8; ++c) {
      int v = cnt[c * 64 + tid];
      int x = v;
#pragma unroll
      for (int off = 1; off < 64; off <<= 1) {
        int q = __shfl_up(x, off, 64);
        if (tid >= off) x += q;
      }
      cnt[c * 64 + tid] = carry + x - v;
      carry += __shfl(x, 63, 64);
    }
  }
  __syncthreads();

  // write global CSR offsets
  const int base = bbase[b];
  for (int j = tid; j < NPP2; j += 256) {
    int node = lo + j;
    if (node < N_NODES) offs[node] = base + cnt[j];
  }
  __syncthreads();

  // pass 2: rank via LDS cursor, place payload
  for (int i = tid; i < n; i += 256) {
    uint2 it = bp[i];
    int r = atomicAdd(&cnt[(int)it.x - lo], 1);
    pairs[base + r] = it.y;
  }
}

// ---------------------------------------------------------------------------
// K3: feat fp32 -> bf16 into A1 columns 0..127 (row stride 256 bf16)
// ---------------------------------------------------------------------------
__global__ __launch_bounds__(256) void k_convert(
    const float* __restrict__ feat, unsigned* __restrict__ A1u) {
  long long idx = (long long)blockIdx.x * 256 + threadIdx.x;
  long long fidx = idx * 8;
  if (fidx >= (long long)N_NODES * IN_F) return;
  int node = (int)(fidx >> 7);
  int c0 = (int)(fidx & 127);
  float4 f0 = *reinterpret_cast<const float4*>(feat + fidx);
  float4 f1 = *reinterpret_cast<const float4*>(feat + fidx + 4);
  uint4 o;
  o.x = f2bf_pair(f0.x, f0.y);
  o.y = f2bf_pair(f0.z, f0.w);
  o.z = f2bf_pair(f1.x, f1.y);
  o.w = f2bf_pair(f1.z, f1.w);
  *reinterpret_cast<uint4*>(A1u + (size_t)node * 128 + (c0 >> 1)) = o;
}

// ---------------------------------------------------------------------------
// K4: W1T[c][k] = bf16( k<128 ? Wself[k][c] : Wneigh[k-128][c] )
// ---------------------------------------------------------------------------
__global__ __launch_bounds__(256) void k_prepw(
    const float* __restrict__ Wself, const float* __restrict__ Wneigh,
    unsigned short* __restrict__ W1T) {
  int c = blockIdx.x;
  int k = threadIdx.x;
  float v = (k < 128) ? Wself[(size_t)k * HID_F + c]
                      : Wneigh[(size_t)(k - 128) * HID_F + c];
  W1T[(size_t)c * 256 + k] = f2bf(v);
}

// ---------------------------------------------------------------------------
// K5: pull-gather, 4-edge-parallel (validated round 5)
// ---------------------------------------------------------------------------
__global__ __launch_bounds__(256) void k_gather(
    const int* __restrict__ offs, const unsigned* __restrict__ pairs,
    unsigned* __restrict__ A1u) {
  int node = blockIdx.x * 4 + (threadIdx.x >> 6);
  if (node >= N_NODES) return;
  const int lane = threadIdx.x & 63;
  const int g = lane >> 4;
  const int cl = lane & 15;
  const int start = offs[node], end = offs[node + 1];
  const int deg = end - start;

  float acc[8] = {0.f, 0.f, 0.f, 0.f, 0.f, 0.f, 0.f, 0.f};

  for (int k0 = start; k0 < end; k0 += 64) {
    unsigned pr = 0;
    if (k0 + lane < end) pr = pairs[k0 + lane];
    const int cnt = min(64, end - k0);
    const int nsteps = (cnt + 3) >> 2;
    for (int t = 0; t < nsteps; ++t) {
      unsigned uu = (unsigned)__shfl((int)pr, 4 * t + g, 64);
      int s = (int)(uu >> 15);
      float w = __half2float(__ushort_as_half((unsigned short)(uu & 0x7fffu)));
      uint4 f = *reinterpret_cast<const uint4*>(A1u + (size_t)s * 128 + cl * 4);
      acc[0] = fmaf(w, bf_lo(f.x), acc[0]);
      acc[1] = fmaf(w, bf_hi(f.x), acc[1]);
      acc[2] = fmaf(w, bf_lo(f.y), acc[2]);
      acc[3] = fmaf(w, bf_hi(f.y), acc[3]);
      acc[4] = fmaf(w, bf_lo(f.z), acc[4]);
      acc[5] = fmaf(w, bf_hi(f.z), acc[5]);
      acc[6] = fmaf(w, bf_lo(f.w), acc[6]);
      acc[7] = fmaf(w, bf_hi(f.w), acc[7]);
    }
  }

#pragma unroll
  for (int i = 0; i < 8; ++i) {
    acc[i] += __shfl_xor(acc[i], 16, 64);
    acc[i] += __shfl_xor(acc[i], 32, 64);
  }

  if (g == 0) {
    const float inv = (deg > 0) ? (1.0f / (float)deg) : 0.f;
    uint4 o;
    o.x = f2bf_pair(acc[0] * inv, acc[1] * inv);
    o.y = f2bf_pair(acc[2] * inv, acc[3] * inv);
    o.z = f2bf_pair(acc[4] * inv, acc[5] * inv);
    o.w = f2bf_pair(acc[6] * inv, acc[7] * inv);
    *reinterpret_cast<uint4*>(A1u + (size_t)node * 128 + 64 + cl * 4) = o;
  }
}

// ---------------------------------------------------------------------------
// K6: GEMM1, register-resident weights, persistent waves (validated round 8)
// ---------------------------------------------------------------------------
__global__ __launch_bounds__(256, 2) void k_gemm1(
    const unsigned short* __restrict__ A1, const unsigned short* __restrict__ W1T,
    const float* __restrict__ bias, unsigned short* __restrict__ y,
    float* __restrict__ colpart) {
  const int lane = threadIdx.x & 63;
  const int wid = threadIdx.x >> 6;
  const int l16 = lane & 15, lk = lane >> 4;
  const int h0 = wid * 64;

  bf16x8 wreg[8][4];
#pragma unroll
  for (int ks = 0; ks < 8; ++ks)
#pragma unroll
    for (int m = 0; m < 4; ++m)
      wreg[ks][m] = *reinterpret_cast<const bf16x8*>(
          W1T + (size_t)(h0 + m * 16 + l16) * 256 + ks * 32 + lk * 8);

  float4 bias4[4];
#pragma unroll
  for (int m = 0; m < 4; ++m)
    bias4[m] = *reinterpret_cast<const float4*>(bias + h0 + m * 16 + lk * 4);

  float sacc[4][4] = {};
  float qacc[4][4] = {};

  for (int t = blockIdx.x; t < NSUB; t += G1_GRID) {
    const int nbase = t * 32;
    f32x4 acc[4][2];
#pragma unroll
    for (int m = 0; m < 4; ++m)
#pragma unroll
      for (int n = 0; n < 2; ++n) acc[m][n] = (f32x4){0.f, 0.f, 0.f, 0.f};

#pragma unroll
    for (int ks = 0; ks < 8; ++ks) {
      bf16x8 bf0 = *reinterpret_cast<const bf16x8*>(
          A1 + (size_t)(nbase + l16) * 256 + ks * 32 + lk * 8);
      bf16x8 bf1 = *reinterpret_cast<const bf16x8*>(
          A1 + (size_t)(nbase + 16 + l16) * 256 + ks * 32 + lk * 8);
#pragma unroll
      for (int m = 0; m < 4; ++m) {
        acc[m][0] = __builtin_amdgcn_mfma_f32_16x16x32_bf16(
            wreg[ks][m], bf0, acc[m][0], 0, 0, 0);
        acc[m][1] = __builtin_amdgcn_mfma_f32_16x16x32_bf16(
            wreg[ks][m], bf1, acc[m][1], 0, 0, 0);
      }
    }

#pragma unroll
    for (int m = 0; m < 4; ++m) {
#pragma unroll
      for (int n = 0; n < 2; ++n) {
        float t0 = fmaxf(acc[m][n][0] + bias4[m].x, 0.f);
        float t1 = fmaxf(acc[m][n][1] + bias4[m].y, 0.f);
        float t2 = fmaxf(acc[m][n][2] + bias4[m].z, 0.f);
        float t3 = fmaxf(acc[m][n][3] + bias4[m].w, 0.f);
        uint2 pk;
        pk.x = f2bf_pair(t0, t1);
        pk.y = f2bf_pair(t2, t3);
        *reinterpret_cast<uint2*>(
            y + (size_t)(nbase + n * 16 + l16) * 256 + h0 + m * 16 + lk * 4) = pk;
        sacc[m][0] += t0; sacc[m][1] += t1; sacc[m][2] += t2; sacc[m][3] += t3;
        qacc[m][0] = fmaf(t0, t0, qacc[m][0]);
        qacc[m][1] = fmaf(t1, t1, qacc[m][1]);
        qacc[m][2] = fmaf(t2, t2, qacc[m][2]);
        qacc[m][3] = fmaf(t3, t3, qacc[m][3]);
      }
    }
  }

#pragma unroll
  for (int m = 0; m < 4; ++m) {
#pragma unroll
    for (int r = 0; r < 4; ++r) {
      float s = sacc[m][r], q = qacc[m][r];
      s += __shfl_xor(s, 1, 64); s += __shfl_xor(s, 2, 64);
      s += __shfl_xor(s, 4, 64); s += __shfl_xor(s, 8, 64);
      q += __shfl_xor(q, 1, 64); q += __shfl_xor(q, 2, 64);
      q += __shfl_xor(q, 4, 64); q += __shfl_xor(q, 8, 64);
      if (l16 == 0) {
        int h = h0 + m * 16 + lk * 4 + r;
        colpart[(size_t)blockIdx.x * 512 + h] = s;
        colpart[(size_t)blockIdx.x * 512 + 256 + h] = q;
      }
    }
  }
}

// ---------------------------------------------------------------------------
// K6b: reduce colpart slab -> colsum/colsq (pre-zeroed)
// ---------------------------------------------------------------------------
__global__ __launch_bounds__(256) void k_redstats(
    const float* __restrict__ colpart, float* __restrict__ colsum,
    float* __restrict__ colsq) {
  const int h = threadIdx.x;
  float s = 0.f, q = 0.f;
  for (int j = blockIdx.x; j < G1_GRID; j += gridDim.x) {
    s += colpart[(size_t)j * 512 + h];
    q += colpart[(size_t)j * 512 + 256 + h];
  }
  atomicAdd(&colsum[h], s);
  atomicAdd(&colsq[h], q);
}

// ---------------------------------------------------------------------------
// K7: BN fold -> W2T[o][h] bf16 (o padded to 192), b2[o] f32
// ---------------------------------------------------------------------------
__global__ __launch_bounds__(256) void k_finalize(
    const float* __restrict__ colsum, const float* __restrict__ colsq,
    const float* __restrict__ gamma, const float* __restrict__ beta,
    const float* __restrict__ fcW, const float* __restrict__ fcb,
    unsigned short* __restrict__ W2T, float* __restrict__ b2) {
  const float invN = 1.0f / (float)N_NODES;
  if (blockIdx.x < 192) {
    int o = blockIdx.x, h = threadIdx.x;
    unsigned short v = 0;
    if (o < OUT_F) {
      float mu = colsum[h] * invN;
      float var = colsq[h] * invN - mu * mu;
      float rs = rsqrtf(var + BN_EPS) * gamma[h];
      v = f2bf(fcW[(size_t)h * OUT_F + o] * rs);
    }
    W2T[(size_t)o * 256 + h] = v;
  } else if (threadIdx.x < OUT_F) {
    int o = threadIdx.x;
    float acc = fcb[o];
    for (int h = 0; h < HID_F; ++h) {
      float mu = colsum[h] * invN;
      float var = colsq[h] * invN - mu * mu;
      float rs = rsqrtf(var + BN_EPS) * gamma[h];
      acc += (beta[h] - mu * rs) * fcW[(size_t)h * OUT_F + o];
    }
    b2[o] = acc;
  }
}

// ---------------------------------------------------------------------------
// K8: GEMM2, register-resident weights, persistent waves (validated round 8)
// ---------------------------------------------------------------------------
__global__ __launch_bounds__(256, 2) void k_gemm2(
    const unsigned short* __restrict__ y, const unsigned short* __restrict__ W2T,
    const float* __restrict__ b2, float* __restrict__ out) {
  const int lane = threadIdx.x & 63;
  const int wid = threadIdx.x >> 6;
  const int l16 = lane & 15, lk = lane >> 4;
  const int wn = wid & 1;
  const int o0 = (wid >> 1) * 80;

  bf16x8 wreg[8][5];
#pragma unroll
  for (int ks = 0; ks < 8; ++ks)
#pragma unroll
    for (int m = 0; m < 5; ++m)
      wreg[ks][m] = *reinterpret_cast<const bf16x8*>(
          W2T + (size_t)(o0 + m * 16 + l16) * 256 + ks * 32 + lk * 8);

  float4 b24[5];
#pragma unroll
  for (int m = 0; m < 5; ++m)
    b24[m] = *reinterpret_cast<const float4*>(b2 + o0 + m * 16 + lk * 4);

  for (int t = blockIdx.x; t < NT2; t += G2_GRID) {
    const int nb = t * 64 + wn * 32;
    const int r0 = min(nb + l16, N_NODES - 1);
    const int r1 = min(nb + 16 + l16, N_NODES - 1);

    f32x4 acc[5][2];
#pragma unroll
    for (int m = 0; m < 5; ++m)
#pragma unroll
      for (int n = 0; n < 2; ++n) acc[m][n] = (f32x4){0.f, 0.f, 0.f, 0.f};

#pragma unroll
    for (int ks = 0; ks < 8; ++ks) {
      bf16x8 bf0 = *reinterpret_cast<const bf16x8*>(
          y + (size_t)r0 * 256 + ks * 32 + lk * 8);
      bf16x8 bf1 = *reinterpret_cast<const bf16x8*>(
          y + (size_t)r1 * 256 + ks * 32 + lk * 8);
#pragma unroll
      for (int m = 0; m < 5; ++m) {
        acc[m][0] = __builtin_amdgcn_mfma_f32_16x16x32_bf16(
            wreg[ks][m], bf0, acc[m][0], 0, 0, 0);
        acc[m][1] = __builtin_amdgcn_mfma_f32_16x16x32_bf16(
            wreg[ks][m], bf1, acc[m][1], 0, 0, 0);
      }
    }

#pragma unroll
    for (int n = 0; n < 2; ++n) {
      const int fb = nb + n * 16;
      if (fb < N_NODES) {
#pragma unroll
        for (int m = 0; m < 5; ++m) {
          float4 v;
          v.x = acc[m][n][0] + b24[m].x;
          v.y = acc[m][n][1] + b24[m].y;
          v.z = acc[m][n][2] + b24[m].z;
          v.w = acc[m][n][3] + b24[m].w;
          *reinterpret_cast<float4*>(
              out + (size_t)(fb + l16) * OUT_F + o0 + m * 16 + lk * 4) = v;
        }
      }
    }
  }
}

// ---------------------------------------------------------------------------
extern "C" void kernel_launch(void* const* d_in, const int* in_sizes, int n_in,
                              void* d_out, int out_size, void* d_ws,
                              size_t ws_size, hipStream_t stream) {
  const float* feat   = (const float*)d_in[0];
  const int*   src    = (const int*)d_in[1];
  const int*   dst    = (const int*)d_in[2];
  const float* ew     = (const float*)d_in[3];
  const float* Wself  = (const float*)d_in[4];
  const float* Wneigh = (const float*)d_in[5];
  const float* bias   = (const float*)d_in[6];
  const float* gamma  = (const float*)d_in[7];
  const float* beta   = (const float*)d_in[8];
  const float* fcW    = (const float*)d_in[9];
  const float* fcb    = (const float*)d_in[10];
  float* out = (float*)d_out;

  char* ws = (char*)d_ws;
  // layout (bytes):
  //   [0,      1,024)      gcnt    256 i32         (zeroed)
  //   [1,024,  2,048)      colsum  256 f32         (zeroed)
  //   [2,048,  3,072)      colsq   256 f32         (zeroed)
  //   [3,072,  4,100)      bbase   257 i32
  //   [4,224,  404,228)    offs    (N+1) i32
  //   [404,480, 6,804,480) pairs   E u32
  //   [6,804,480, 23,581,696)  bucket 256*8192 uint2
  //   [23,581,696, 74,781,696) A1     N*256 bf16 (feat | neigh)
  //   [74,781,696, 74,912,768) W1T    256*256 bf16
  //   [74,912,768, 75,011,072) W2T    192*256 bf16
  //   [75,011,072, 75,011,712) b2     160 f32
  //   [75,011,712, 126,211,712) y     N*256 bf16
  //   [126,211,712, 127,260,288) colpart 512*512 f32
  int*            gcnt    = (int*)(ws + 0);
  float*          colsum  = (float*)(ws + 1024);
  float*          colsq   = (float*)(ws + 2048);
  int*            bbase   = (int*)(ws + 3072);
  int*            offs    = (int*)(ws + 4224);
  unsigned*       pairs   = (unsigned*)(ws + 404480);
  uint2*          bucket  = (uint2*)(ws + 6804480);
  unsigned*       A1u     = (unsigned*)(ws + 23581696);
  unsigned short* A1      = (unsigned short*)(ws + 23581696);
  unsigned short* W1T     = (unsigned short*)(ws + 74781696);
  unsigned short* W2T     = (unsigned short*)(ws + 74912768);
  float*          b2      = (float*)(ws + 75011072);
  unsigned short* y       = (unsigned short*)(ws + 75011712);
  float*          colpart = (float*)(ws + 126211712);

  hipMemsetAsync(ws, 0, 3072, stream);

  dim3 b256(256);
  k_convert<<<dim3((N_NODES * IN_F / 8 + 255) / 256), b256, 0, stream>>>(
      feat, A1u);
  k_prepw<<<dim3(256), b256, 0, stream>>>(Wself, Wneigh, W1T);
  k_bucket<<<dim3(NCHUNK), b256, 0, stream>>>(src, dst, ew, gcnt, bucket);
  k_scanb<<<dim3(1), b256, 0, stream>>>(gcnt, bbase, offs);
  k_csr<<<dim3(NBKT), b256, 0, stream>>>(bucket, gcnt, bbase, offs, pairs);
  k_gather<<<dim3((N_NODES + 3) / 4), b256, 0, stream>>>(offs, pairs, A1u);
  k_gemm1<<<dim3(G1_GRID), b256, 0, stream>>>(A1, W1T, bias, y, colpart);
  k_redstats<<<dim3(32), b256, 0, stream>>>(colpart, colsum, colsq);
  k_finalize<<<dim3(193), b256, 0, stream>>>(
      colsum, colsq, gamma, beta, fcW, fcb, W2T, b2);
  k_gemm2<<<dim3(G2_GRID), b256, 0, stream>>>(y, W2T, b2, out);
}

// Round 11
// 223.124 us; speedup vs baseline: 1.8121x; 1.0209x over previous
//
#include <hip/hip_runtime.h>
#include <hip/hip_fp16.h>

#define N_NODES 100000
#define N_EDGES 1600000
#define IN_F    128
#define HID_F   256
#define OUT_F   160
#define BN_EPS  1e-5f

#define EPB     4096                         // edges per bucket-block
#define NCHUNK  ((N_EDGES + EPB - 1) / EPB)  // 391
#define NBKT    256                          // buckets (node ranges)
#define NPP2    391                          // nodes per bucket (256*391 >= N)
#define BCAP2   8192                         // bucket capacity (mean 6250)
#define NSUB    (N_NODES / 32)               // 3125 32-node tiles (exact)
#define G1_GRID 512
#define NT2     ((N_NODES + 63) / 64)        // 1563 64-node tiles
#define G2_GRID 512
#define CVT_BLOCKS ((N_NODES * IN_F / 8 + 255) / 256)  // 6250

typedef __attribute__((ext_vector_type(8))) short bf16x8;
typedef __attribute__((ext_vector_type(4))) float f32x4;

static __device__ inline unsigned short f2bf(float x) {
  unsigned u = __float_as_uint(x);
  return (unsigned short)((u + 0x7fffu + ((u >> 16) & 1u)) >> 16);
}
static __device__ inline unsigned f2bf_pair(float lo, float hi) {
  return (unsigned)f2bf(lo) | ((unsigned)f2bf(hi) << 16);
}
static __device__ inline float bf_lo(unsigned u) {
  return __uint_as_float(u << 16);
}
static __device__ inline float bf_hi(unsigned u) {
  return __uint_as_float(u & 0xffff0000u);
}

// ---------------------------------------------------------------------------
// K0: single-pass 256-way bucket scatter (validated round 10)
// ---------------------------------------------------------------------------
__global__ __launch_bounds__(256) void k_bucket(
    const int* __restrict__ src, const int* __restrict__ dst,
    const float* __restrict__ ew, int* __restrict__ gcnt,
    uint2* __restrict__ bucket) {
  __shared__ int bcnt[NBKT];
  __shared__ int bcur[NBKT];
  const int tid = threadIdx.x;
  const int e0 = blockIdx.x * EPB;
  bcnt[tid] = 0;
  __syncthreads();
  int ed[16];
  unsigned pd[16];
#pragma unroll
  for (int i = 0; i < 16; ++i) {
    int e = e0 + i * 256 + tid;
    int d = -1;
    unsigned p = 0;
    if (e < N_EDGES) {
      d = dst[e];
      unsigned hb = (unsigned)__half_as_ushort(__float2half(ew[e])) & 0x7fffu;
      p = ((unsigned)src[e] << 15) | hb;
      atomicAdd(&bcnt[d / NPP2], 1);
    }
    ed[i] = d;
    pd[i] = p;
  }
  __syncthreads();
  bcur[tid] = atomicAdd(&gcnt[tid], bcnt[tid]);
  __syncthreads();
#pragma unroll
  for (int i = 0; i < 16; ++i) {
    if (ed[i] >= 0) {
      int b = ed[i] / NPP2;
      int pos = atomicAdd(&bcur[b], 1);
      if (pos < BCAP2)
        bucket[(size_t)b * BCAP2 + pos] = make_uint2((unsigned)ed[i], pd[i]);
    }
  }
}

// ---------------------------------------------------------------------------
// K0c: per-bucket LDS counting sort -> offs + pairs. Computes its own bucket
// base via a masked block-reduce over gcnt (no scanb kernel). All per-edge
// atomics are LDS. No global atomics.
// ---------------------------------------------------------------------------
__global__ __launch_bounds__(256) void k_csr(
    const uint2* __restrict__ bucket, const int* __restrict__ gcnt,
    int* __restrict__ offs, unsigned* __restrict__ pairs) {
  __shared__ int cnt[512];
  __shared__ int wred[4];
  const int b = blockIdx.x;
  const int tid = threadIdx.x;
  const int lo = b * NPP2;
  const int n = min(gcnt[b], BCAP2);
  const uint2* bp = bucket + (size_t)b * BCAP2;

  // bucket base = sum of gcnt[j<b]
  int v = (tid < b) ? gcnt[tid] : 0;
  int x = v;
#pragma unroll
  for (int off = 1; off < 64; off <<= 1) x += __shfl_xor(x, off, 64);
  if ((tid & 63) == 0) wred[tid >> 6] = x;
  cnt[tid] = 0;
  cnt[tid + 256] = 0;
  __syncthreads();
  const int base = wred[0] + wred[1] + wred[2] + wred[3];

  // pass 1: LDS histogram
  for (int i = tid; i < n; i += 256)
    atomicAdd(&cnt[(int)bp[i].x - lo], 1);
  __syncthreads();

  // exclusive scan over 512 counters (wave 0, 8 shfl-chunks with carry)
  if (tid < 64) {
    int carry = 0;
#pragma unroll
    for (int c = 0; c < 8; ++c) {
      int cv = cnt[c * 64 + tid];
      int cx = cv;
#pragma unroll
      for (int off = 1; off < 64; off <<= 1) {
        int q = __shfl_up(cx, off, 64);
        if (tid >= off) cx += q;
      }
      cnt[c * 64 + tid] = carry + cx - cv;
      carry += __shfl(cx, 63, 64);
    }
  }
  __syncthreads();

  // write global CSR offsets
  for (int j = tid; j < NPP2; j += 256) {
    int node = lo + j;
    if (node < N_NODES) offs[node] = base + cnt[j];
  }
  if (b == 0 && tid == 0) offs[N_NODES] = N_EDGES;
  __syncthreads();

  // pass 2: rank via LDS cursor, place payload
  for (int i = tid; i < n; i += 256) {
    uint2 it = bp[i];
    int r = atomicAdd(&cnt[(int)it.x - lo], 1);
    pairs[base + r] = it.y;
  }
}

// ---------------------------------------------------------------------------
// K3: feat fp32 -> bf16 into A1 columns 0..127; tail blocks build W1T
// ---------------------------------------------------------------------------
__global__ __launch_bounds__(256) void k_convert(
    const float* __restrict__ feat, unsigned* __restrict__ A1u,
    const float* __restrict__ Wself, const float* __restrict__ Wneigh,
    unsigned short* __restrict__ W1T) {
  if (blockIdx.x >= CVT_BLOCKS) {
    // W1T[c][k] = bf16( k<128 ? Wself[k][c] : Wneigh[k-128][c] )
    int c = blockIdx.x - CVT_BLOCKS;   // 0..255
    int k = threadIdx.x;               // 0..255
    float v = (k < 128) ? Wself[(size_t)k * HID_F + c]
                        : Wneigh[(size_t)(k - 128) * HID_F + c];
    W1T[(size_t)c * 256 + k] = f2bf(v);
    return;
  }
  long long idx = (long long)blockIdx.x * 256 + threadIdx.x;
  long long fidx = idx * 8;
  if (fidx >= (long long)N_NODES * IN_F) return;
  int node = (int)(fidx >> 7);
  int c0 = (int)(fidx & 127);
  float4 f0 = *reinterpret_cast<const float4*>(feat + fidx);
  float4 f1 = *reinterpret_cast<const float4*>(feat + fidx + 4);
  uint4 o;
  o.x = f2bf_pair(f0.x, f0.y);
  o.y = f2bf_pair(f0.z, f0.w);
  o.z = f2bf_pair(f1.x, f1.y);
  o.w = f2bf_pair(f1.z, f1.w);
  *reinterpret_cast<uint4*>(A1u + (size_t)node * 128 + (c0 >> 1)) = o;
}

// ---------------------------------------------------------------------------
// K5: pull-gather, 4-edge-parallel, 2x unrolled (dual loads in flight).
// OOB lanes carry pr=0 -> s=0, w=+0.0, so overhang steps are harmless
// (shfl index <= 63 holds for all degrees; see round-11 derivation).
// ---------------------------------------------------------------------------
__global__ __launch_bounds__(256) void k_gather(
    const int* __restrict__ offs, const unsigned* __restrict__ pairs,
    unsigned* __restrict__ A1u) {
  int node = blockIdx.x * 4 + (threadIdx.x >> 6);
  if (node >= N_NODES) return;
  const int lane = threadIdx.x & 63;
  const int g = lane >> 4;
  const int cl = lane & 15;
  const int start = offs[node], end = offs[node + 1];
  const int deg = end - start;
  const unsigned* fbase = A1u + cl * 4;

  float acc[8] = {0.f, 0.f, 0.f, 0.f, 0.f, 0.f, 0.f, 0.f};

  for (int k0 = start; k0 < end; k0 += 64) {
    unsigned pr = 0;
    if (k0 + lane < end) pr = pairs[k0 + lane];
    const int cnt = min(64, end - k0);
    const int nsteps = (cnt + 3) >> 2;
    for (int t = 0; t < nsteps; t += 2) {
      unsigned uu0 = (unsigned)__shfl((int)pr, 4 * t + g, 64);
      unsigned uu1 = (unsigned)__shfl((int)pr, 4 * (t + 1) + g, 64);
      int s0 = (int)(uu0 >> 15);
      int s1 = (int)(uu1 >> 15);
      float w0 = __half2float(__ushort_as_half((unsigned short)(uu0 & 0x7fffu)));
      float w1 = __half2float(__ushort_as_half((unsigned short)(uu1 & 0x7fffu)));
      uint4 f0 = *reinterpret_cast<const uint4*>(fbase + (size_t)s0 * 128);
      uint4 f1 = *reinterpret_cast<const uint4*>(fbase + (size_t)s1 * 128);
      acc[0] = fmaf(w0, bf_lo(f0.x), acc[0]);
      acc[1] = fmaf(w0, bf_hi(f0.x), acc[1]);
      acc[2] = fmaf(w0, bf_lo(f0.y), acc[2]);
      acc[3] = fmaf(w0, bf_hi(f0.y), acc[3]);
      acc[4] = fmaf(w0, bf_lo(f0.z), acc[4]);
      acc[5] = fmaf(w0, bf_hi(f0.z), acc[5]);
      acc[6] = fmaf(w0, bf_lo(f0.w), acc[6]);
      acc[7] = fmaf(w0, bf_hi(f0.w), acc[7]);
      acc[0] = fmaf(w1, bf_lo(f1.x), acc[0]);
      acc[1] = fmaf(w1, bf_hi(f1.x), acc[1]);
      acc[2] = fmaf(w1, bf_lo(f1.y), acc[2]);
      acc[3] = fmaf(w1, bf_hi(f1.y), acc[3]);
      acc[4] = fmaf(w1, bf_lo(f1.z), acc[4]);
      acc[5] = fmaf(w1, bf_hi(f1.z), acc[5]);
      acc[6] = fmaf(w1, bf_lo(f1.w), acc[6]);
      acc[7] = fmaf(w1, bf_hi(f1.w), acc[7]);
    }
  }

#pragma unroll
  for (int i = 0; i < 8; ++i) {
    acc[i] += __shfl_xor(acc[i], 16, 64);
    acc[i] += __shfl_xor(acc[i], 32, 64);
  }

  if (g == 0) {
    const float inv = (deg > 0) ? (1.0f / (float)deg) : 0.f;
    uint4 o;
    o.x = f2bf_pair(acc[0] * inv, acc[1] * inv);
    o.y = f2bf_pair(acc[2] * inv, acc[3] * inv);
    o.z = f2bf_pair(acc[4] * inv, acc[5] * inv);
    o.w = f2bf_pair(acc[6] * inv, acc[7] * inv);
    *reinterpret_cast<uint4*>(A1u + (size_t)node * 128 + 64 + cl * 4) = o;
  }
}

// ---------------------------------------------------------------------------
// K6: GEMM1, register-resident weights, persistent waves (validated round 8)
// ---------------------------------------------------------------------------
__global__ __launch_bounds__(256, 2) void k_gemm1(
    const unsigned short* __restrict__ A1, const unsigned short* __restrict__ W1T,
    const float* __restrict__ bias, unsigned short* __restrict__ y,
    float* __restrict__ colpart) {
  const int lane = threadIdx.x & 63;
  const int wid = threadIdx.x >> 6;
  const int l16 = lane & 15, lk = lane >> 4;
  const int h0 = wid * 64;

  bf16x8 wreg[8][4];
#pragma unroll
  for (int ks = 0; ks < 8; ++ks)
#pragma unroll
    for (int m = 0; m < 4; ++m)
      wreg[ks][m] = *reinterpret_cast<const bf16x8*>(
          W1T + (size_t)(h0 + m * 16 + l16) * 256 + ks * 32 + lk * 8);

  float4 bias4[4];
#pragma unroll
  for (int m = 0; m < 4; ++m)
    bias4[m] = *reinterpret_cast<const float4*>(bias + h0 + m * 16 + lk * 4);

  float sacc[4][4] = {};
  float qacc[4][4] = {};

  for (int t = blockIdx.x; t < NSUB; t += G1_GRID) {
    const int nbase = t * 32;
    f32x4 acc[4][2];
#pragma unroll
    for (int m = 0; m < 4; ++m)
#pragma unroll
      for (int n = 0; n < 2; ++n) acc[m][n] = (f32x4){0.f, 0.f, 0.f, 0.f};

#pragma unroll
    for (int ks = 0; ks < 8; ++ks) {
      bf16x8 bf0 = *reinterpret_cast<const bf16x8*>(
          A1 + (size_t)(nbase + l16) * 256 + ks * 32 + lk * 8);
      bf16x8 bf1 = *reinterpret_cast<const bf16x8*>(
          A1 + (size_t)(nbase + 16 + l16) * 256 + ks * 32 + lk * 8);
#pragma unroll
      for (int m = 0; m < 4; ++m) {
        acc[m][0] = __builtin_amdgcn_mfma_f32_16x16x32_bf16(
            wreg[ks][m], bf0, acc[m][0], 0, 0, 0);
        acc[m][1] = __builtin_amdgcn_mfma_f32_16x16x32_bf16(
            wreg[ks][m], bf1, acc[m][1], 0, 0, 0);
      }
    }

#pragma unroll
    for (int m = 0; m < 4; ++m) {
#pragma unroll
      for (int n = 0; n < 2; ++n) {
        float t0 = fmaxf(acc[m][n][0] + bias4[m].x, 0.f);
        float t1 = fmaxf(acc[m][n][1] + bias4[m].y, 0.f);
        float t2 = fmaxf(acc[m][n][2] + bias4[m].z, 0.f);
        float t3 = fmaxf(acc[m][n][3] + bias4[m].w, 0.f);
        uint2 pk;
        pk.x = f2bf_pair(t0, t1);
        pk.y = f2bf_pair(t2, t3);
        *reinterpret_cast<uint2*>(
            y + (size_t)(nbase + n * 16 + l16) * 256 + h0 + m * 16 + lk * 4) = pk;
        sacc[m][0] += t0; sacc[m][1] += t1; sacc[m][2] += t2; sacc[m][3] += t3;
        qacc[m][0] = fmaf(t0, t0, qacc[m][0]);
        qacc[m][1] = fmaf(t1, t1, qacc[m][1]);
        qacc[m][2] = fmaf(t2, t2, qacc[m][2]);
        qacc[m][3] = fmaf(t3, t3, qacc[m][3]);
      }
    }
  }

#pragma unroll
  for (int m = 0; m < 4; ++m) {
#pragma unroll
    for (int r = 0; r < 4; ++r) {
      float s = sacc[m][r], q = qacc[m][r];
      s += __shfl_xor(s, 1, 64); s += __shfl_xor(s, 2, 64);
      s += __shfl_xor(s, 4, 64); s += __shfl_xor(s, 8, 64);
      q += __shfl_xor(q, 1, 64); q += __shfl_xor(q, 2, 64);
      q += __shfl_xor(q, 4, 64); q += __shfl_xor(q, 8, 64);
      if (l16 == 0) {
        int h = h0 + m * 16 + lk * 4 + r;
        colpart[(size_t)blockIdx.x * 512 + h] = s;
        colpart[(size_t)blockIdx.x * 512 + 256 + h] = q;
      }
    }
  }
}

// ---------------------------------------------------------------------------
// K6b: reduce colpart slab -> colsum/colsq (pre-zeroed)
// ---------------------------------------------------------------------------
__global__ __launch_bounds__(256) void k_redstats(
    const float* __restrict__ colpart, float* __restrict__ colsum,
    float* __restrict__ colsq) {
  const int h = threadIdx.x;
  float s = 0.f, q = 0.f;
  for (int j = blockIdx.x; j < G1_GRID; j += gridDim.x) {
    s += colpart[(size_t)j * 512 + h];
    q += colpart[(size_t)j * 512 + 256 + h];
  }
  atomicAdd(&colsum[h], s);
  atomicAdd(&colsq[h], q);
}

// ---------------------------------------------------------------------------
// K7: BN fold -> W2T[o][h] bf16 (o padded to 192), b2[o] f32
// ---------------------------------------------------------------------------
__global__ __launch_bounds__(256) void k_finalize(
    const float* __restrict__ colsum, const float* __restrict__ colsq,
    const float* __restrict__ gamma, const float* __restrict__ beta,
    const float* __restrict__ fcW, const float* __restrict__ fcb,
    unsigned short* __restrict__ W2T, float* __restrict__ b2) {
  const float invN = 1.0f / (float)N_NODES;
  if (blockIdx.x < 192) {
    int o = blockIdx.x, h = threadIdx.x;
    unsigned short v = 0;
    if (o < OUT_F) {
      float mu = colsum[h] * invN;
      float var = colsq[h] * invN - mu * mu;
      float rs = rsqrtf(var + BN_EPS) * gamma[h];
      v = f2bf(fcW[(size_t)h * OUT_F + o] * rs);
    }
    W2T[(size_t)o * 256 + h] = v;
  } else if (threadIdx.x < OUT_F) {
    int o = threadIdx.x;
    float acc = fcb[o];
    for (int h = 0; h < HID_F; ++h) {
      float mu = colsum[h] * invN;
      float var = colsq[h] * invN - mu * mu;
      float rs = rsqrtf(var + BN_EPS) * gamma[h];
      acc += (beta[h] - mu * rs) * fcW[(size_t)h * OUT_F + o];
    }
    b2[o] = acc;
  }
}

// ---------------------------------------------------------------------------
// K8: GEMM2, register-resident weights, persistent waves (validated round 8)
// ---------------------------------------------------------------------------
__global__ __launch_bounds__(256, 2) void k_gemm2(
    const unsigned short* __restrict__ y, const unsigned short* __restrict__ W2T,
    const float* __restrict__ b2, float* __restrict__ out) {
  const int lane = threadIdx.x & 63;
  const int wid = threadIdx.x >> 6;
  const int l16 = lane & 15, lk = lane >> 4;
  const int wn = wid & 1;
  const int o0 = (wid >> 1) * 80;

  bf16x8 wreg[8][5];
#pragma unroll
  for (int ks = 0; ks < 8; ++ks)
#pragma unroll
    for (int m = 0; m < 5; ++m)
      wreg[ks][m] = *reinterpret_cast<const bf16x8*>(
          W2T + (size_t)(o0 + m * 16 + l16) * 256 + ks * 32 + lk * 8);

  float4 b24[5];
#pragma unroll
  for (int m = 0; m < 5; ++m)
    b24[m] = *reinterpret_cast<const float4*>(b2 + o0 + m * 16 + lk * 4);

  for (int t = blockIdx.x; t < NT2; t += G2_GRID) {
    const int nb = t * 64 + wn * 32;
    const int r0 = min(nb + l16, N_NODES - 1);
    const int r1 = min(nb + 16 + l16, N_NODES - 1);

    f32x4 acc[5][2];
#pragma unroll
    for (int m = 0; m < 5; ++m)
#pragma unroll
      for (int n = 0; n < 2; ++n) acc[m][n] = (f32x4){0.f, 0.f, 0.f, 0.f};

#pragma unroll
    for (int ks = 0; ks < 8; ++ks) {
      bf16x8 bf0 = *reinterpret_cast<const bf16x8*>(
          y + (size_t)r0 * 256 + ks * 32 + lk * 8);
      bf16x8 bf1 = *reinterpret_cast<const bf16x8*>(
          y + (size_t)r1 * 256 + ks * 32 + lk * 8);
#pragma unroll
      for (int m = 0; m < 5; ++m) {
        acc[m][0] = __builtin_amdgcn_mfma_f32_16x16x32_bf16(
            wreg[ks][m], bf0, acc[m][0], 0, 0, 0);
        acc[m][1] = __builtin_amdgcn_mfma_f32_16x16x32_bf16(
            wreg[ks][m], bf1, acc[m][1], 0, 0, 0);
      }
    }

#pragma unroll
    for (int n = 0; n < 2; ++n) {
      const int fb = nb + n * 16;
      if (fb < N_NODES) {
#pragma unroll
        for (int m = 0; m < 5; ++m) {
          float4 v;
          v.x = acc[m][n][0] + b24[m].x;
          v.y = acc[m][n][1] + b24[m].y;
          v.z = acc[m][n][2] + b24[m].z;
          v.w = acc[m][n][3] + b24[m].w;
          *reinterpret_cast<float4*>(
              out + (size_t)(fb + l16) * OUT_F + o0 + m * 16 + lk * 4) = v;
        }
      }
    }
  }
}

// ---------------------------------------------------------------------------
extern "C" void kernel_launch(void* const* d_in, const int* in_sizes, int n_in,
                              void* d_out, int out_size, void* d_ws,
                              size_t ws_size, hipStream_t stream) {
  const float* feat   = (const float*)d_in[0];
  const int*   src    = (const int*)d_in[1];
  const int*   dst    = (const int*)d_in[2];
  const float* ew     = (const float*)d_in[3];
  const float* Wself  = (const float*)d_in[4];
  const float* Wneigh = (const float*)d_in[5];
  const float* bias   = (const float*)d_in[6];
  const float* gamma  = (const float*)d_in[7];
  const float* beta   = (const float*)d_in[8];
  const float* fcW    = (const float*)d_in[9];
  const float* fcb    = (const float*)d_in[10];
  float* out = (float*)d_out;

  char* ws = (char*)d_ws;
  // layout (bytes):
  //   [0,      1,024)      gcnt    256 i32         (zeroed)
  //   [1,024,  2,048)      colsum  256 f32         (zeroed)
  //   [2,048,  3,072)      colsq   256 f32         (zeroed)
  //   [4,224,  404,228)    offs    (N+1) i32
  //   [404,480, 6,804,480) pairs   E u32
  //   [6,804,480, 23,581,696)  bucket 256*8192 uint2
  //   [23,581,696, 74,781,696) A1     N*256 bf16 (feat | neigh)
  //   [74,781,696, 74,912,768) W1T    256*256 bf16
  //   [74,912,768, 75,011,072) W2T    192*256 bf16
  //   [75,011,072, 75,011,712) b2     160 f32
  //   [75,011,712, 126,211,712) y     N*256 bf16
  //   [126,211,712, 127,260,288) colpart 512*512 f32
  int*            gcnt    = (int*)(ws + 0);
  float*          colsum  = (float*)(ws + 1024);
  float*          colsq   = (float*)(ws + 2048);
  int*            offs    = (int*)(ws + 4224);
  unsigned*       pairs   = (unsigned*)(ws + 404480);
  uint2*          bucket  = (uint2*)(ws + 6804480);
  unsigned*       A1u     = (unsigned*)(ws + 23581696);
  unsigned short* A1      = (unsigned short*)(ws + 23581696);
  unsigned short* W1T     = (unsigned short*)(ws + 74781696);
  unsigned short* W2T     = (unsigned short*)(ws + 74912768);
  float*          b2      = (float*)(ws + 75011072);
  unsigned short* y       = (unsigned short*)(ws + 75011712);
  float*          colpart = (float*)(ws + 126211712);

  hipMemsetAsync(ws, 0, 3072, stream);

  dim3 b256(256);
  k_convert<<<dim3(CVT_BLOCKS + 256), b256, 0, stream>>>(
      feat, A1u, Wself, Wneigh, W1T);
  k_bucket<<<dim3(NCHUNK), b256, 0, stream>>>(src, dst, ew, gcnt, bucket);
  k_csr<<<dim3(NBKT), b256, 0, stream>>>(bucket, gcnt, offs, pairs);
  k_gather<<<dim3((N_NODES + 3) / 4), b256, 0, stream>>>(offs, pairs, A1u);
  k_gemm1<<<dim3(G1_GRID), b256, 0, stream>>>(A1, W1T, bias, y, colpart);
  k_redstats<<<dim3(32), b256, 0, stream>>>(colpart, colsum, colsq);
  k_finalize<<<dim3(193), b256, 0, stream>>>(
      colsum, colsq, gamma, beta, fcW, fcb, W2T, b2);
  k_gemm2<<<dim3(G2_GRID), b256, 0, stream>>>(y, W2T, b2, out);
}

// Round 12
// 212.804 us; speedup vs baseline: 1.9000x; 1.0485x over previous
//
#include <hip/hip_runtime.h>
#include <hip/hip_fp16.h>

#define N_NODES 100000
#define N_EDGES 1600000
#define IN_F    128
#define HID_F   256
#define OUT_F   160
#define BN_EPS  1e-5f

#define EPB     4096                         // edges per bucket-block
#define NCHUNK  ((N_EDGES + EPB - 1) / EPB)  // 391
#define NBKT    256                          // buckets (node ranges)
#define NPP2    391                          // nodes per bucket (256*391 >= N)
#define BCAP2   8192                         // bucket capacity (mean 6250)
#define NSUB    (N_NODES / 32)               // 3125 32-node tiles (exact)
#define G1_GRID 512
#define NT2     ((N_NODES + 63) / 64)        // 1563 64-node tiles
#define G2_GRID 512
#define CVT_BLOCKS ((N_NODES * IN_F / 8 + 255) / 256)  // 6250

typedef __attribute__((ext_vector_type(8))) short bf16x8;
typedef __attribute__((ext_vector_type(4))) float f32x4;

static __device__ inline unsigned short f2bf(float x) {
  unsigned u = __float_as_uint(x);
  return (unsigned short)((u + 0x7fffu + ((u >> 16) & 1u)) >> 16);
}
static __device__ inline unsigned f2bf_pair(float lo, float hi) {
  return (unsigned)f2bf(lo) | ((unsigned)f2bf(hi) << 16);
}
static __device__ inline float bf_lo(unsigned u) {
  return __uint_as_float(u << 16);
}
static __device__ inline float bf_hi(unsigned u) {
  return __uint_as_float(u & 0xffff0000u);
}

// ---- fp8 e4m3 helpers (HW cvt on gfx950; manual fallback) ------------------
#if __has_builtin(__builtin_amdgcn_cvt_f32_fp8)
#define FP8_DEC(d, s) __builtin_amdgcn_cvt_f32_fp8((int)(d), (s))
#else
static __device__ inline float FP8_DEC(unsigned d, int s) {
  unsigned b = (d >> (s * 8)) & 0xffu;
  unsigned em = b & 0x7fu;
  float mag = (em >= 8) ? __uint_as_float((em << 20) + (120u << 23))
                        : (float)em * 0.001953125f;
  return (b & 0x80u) ? -mag : mag;
}
#endif

#if __has_builtin(__builtin_amdgcn_cvt_pk_fp8_f32)
static __device__ inline unsigned fp8_pack4(float a, float b, float c, float d) {
  int p = __builtin_amdgcn_cvt_pk_fp8_f32(a, b, 0, false);
  p = __builtin_amdgcn_cvt_pk_fp8_f32(c, d, p, true);
  return (unsigned)p;
}
#else
static __device__ inline unsigned fp8_enc1(float x) {
  unsigned u = __float_as_uint(x);
  unsigned s = (u >> 24) & 0x80u;
  float ax = fabsf(x);
  if (ax >= 448.f) return s | 0x7eu;
  if (ax < 0.015625f) {  // subnormal: man = round(ax * 512)
    unsigned m = (unsigned)(ax * 512.f + 0.5f);
    return s | (m > 7u ? 7u : m);
  }
  unsigned b = __float_as_uint(ax);
  b += 0x7ffffu + ((b >> 20) & 1u);           // RNE to 3-bit mantissa
  unsigned exp = (b >> 23) - 120u;            // -127+7
  unsigned man = (b >> 20) & 7u;
  return s | (exp << 3) | man;
}
static __device__ inline unsigned fp8_pack4(float a, float b, float c, float d) {
  return fp8_enc1(a) | (fp8_enc1(b) << 8) | (fp8_enc1(c) << 16) |
         (fp8_enc1(d) << 24);
}
#endif

// ---------------------------------------------------------------------------
// K0: single-pass 256-way bucket scatter (validated round 10)
// ---------------------------------------------------------------------------
__global__ __launch_bounds__(256) void k_bucket(
    const int* __restrict__ src, const int* __restrict__ dst,
    const float* __restrict__ ew, int* __restrict__ gcnt,
    uint2* __restrict__ bucket) {
  __shared__ int bcnt[NBKT];
  __shared__ int bcur[NBKT];
  const int tid = threadIdx.x;
  const int e0 = blockIdx.x * EPB;
  bcnt[tid] = 0;
  __syncthreads();
  int ed[16];
  unsigned pd[16];
#pragma unroll
  for (int i = 0; i < 16; ++i) {
    int e = e0 + i * 256 + tid;
    int d = -1;
    unsigned p = 0;
    if (e < N_EDGES) {
      d = dst[e];
      unsigned hb = (unsigned)__half_as_ushort(__float2half(ew[e])) & 0x7fffu;
      p = ((unsigned)src[e] << 15) | hb;
      atomicAdd(&bcnt[d / NPP2], 1);
    }
    ed[i] = d;
    pd[i] = p;
  }
  __syncthreads();
  bcur[tid] = atomicAdd(&gcnt[tid], bcnt[tid]);
  __syncthreads();
#pragma unroll
  for (int i = 0; i < 16; ++i) {
    if (ed[i] >= 0) {
      int b = ed[i] / NPP2;
      int pos = atomicAdd(&bcur[b], 1);
      if (pos < BCAP2)
        bucket[(size_t)b * BCAP2 + pos] = make_uint2((unsigned)ed[i], pd[i]);
    }
  }
}

// ---------------------------------------------------------------------------
// K0c: per-bucket LDS counting sort -> offs + pairs (validated round 11)
// ---------------------------------------------------------------------------
__global__ __launch_bounds__(256) void k_csr(
    const uint2* __restrict__ bucket, const int* __restrict__ gcnt,
    int* __restrict__ offs, unsigned* __restrict__ pairs) {
  __shared__ int cnt[512];
  __shared__ int wred[4];
  const int b = blockIdx.x;
  const int tid = threadIdx.x;
  const int lo = b * NPP2;
  const int n = min(gcnt[b], BCAP2);
  const uint2* bp = bucket + (size_t)b * BCAP2;

  int v = (tid < b) ? gcnt[tid] : 0;
  int x = v;
#pragma unroll
  for (int off = 1; off < 64; off <<= 1) x += __shfl_xor(x, off, 64);
  if ((tid & 63) == 0) wred[tid >> 6] = x;
  cnt[tid] = 0;
  cnt[tid + 256] = 0;
  __syncthreads();
  const int base = wred[0] + wred[1] + wred[2] + wred[3];

  for (int i = tid; i < n; i += 256)
    atomicAdd(&cnt[(int)bp[i].x - lo], 1);
  __syncthreads();

  if (tid < 64) {
    int carry = 0;
#pragma unroll
    for (int c = 0; c < 8; ++c) {
      int cv = cnt[c * 64 + tid];
      int cx = cv;
#pragma unroll
      for (int off = 1; off < 64; off <<= 1) {
        int q = __shfl_up(cx, off, 64);
        if (tid >= off) cx += q;
      }
      cnt[c * 64 + tid] = carry + cx - cv;
      carry += __shfl(cx, 63, 64);
    }
  }
  __syncthreads();

  for (int j = tid; j < NPP2; j += 256) {
    int node = lo + j;
    if (node < N_NODES) offs[node] = base + cnt[j];
  }
  if (b == 0 && tid == 0) offs[N_NODES] = N_EDGES;
  __syncthreads();

  for (int i = tid; i < n; i += 256) {
    uint2 it = bp[i];
    int r = atomicAdd(&cnt[(int)it.x - lo], 1);
    pairs[base + r] = it.y;
  }
}

// ---------------------------------------------------------------------------
// K3: feat fp32 -> bf16 (A1 cols 0..127) + fp8 e4m3 (Af8); tail builds W1T
// ---------------------------------------------------------------------------
__global__ __launch_bounds__(256) void k_convert(
    const float* __restrict__ feat, unsigned* __restrict__ A1u,
    unsigned* __restrict__ Af8u, const float* __restrict__ Wself,
    const float* __restrict__ Wneigh, unsigned short* __restrict__ W1T) {
  if (blockIdx.x >= CVT_BLOCKS) {
    int c = blockIdx.x - CVT_BLOCKS;   // 0..255
    int k = threadIdx.x;               // 0..255
    float v = (k < 128) ? Wself[(size_t)k * HID_F + c]
                        : Wneigh[(size_t)(k - 128) * HID_F + c];
    W1T[(size_t)c * 256 + k] = f2bf(v);
    return;
  }
  long long idx = (long long)blockIdx.x * 256 + threadIdx.x;
  long long fidx = idx * 8;
  if (fidx >= (long long)N_NODES * IN_F) return;
  int node = (int)(fidx >> 7);
  int c0 = (int)(fidx & 127);
  float4 f0 = *reinterpret_cast<const float4*>(feat + fidx);
  float4 f1 = *reinterpret_cast<const float4*>(feat + fidx + 4);
  uint4 o;
  o.x = f2bf_pair(f0.x, f0.y);
  o.y = f2bf_pair(f0.z, f0.w);
  o.z = f2bf_pair(f1.x, f1.y);
  o.w = f2bf_pair(f1.z, f1.w);
  *reinterpret_cast<uint4*>(A1u + (size_t)node * 128 + (c0 >> 1)) = o;
  uint2 q;
  q.x = fp8_pack4(f0.x, f0.y, f0.z, f0.w);
  q.y = fp8_pack4(f1.x, f1.y, f1.z, f1.w);
  *reinterpret_cast<uint2*>(Af8u + (size_t)node * 32 + (c0 >> 2)) = q;
}

// ---------------------------------------------------------------------------
// K5: pull-gather, 4-edge-parallel, 2x unrolled, fp8 feature reads.
// Lane cl owns feats [cl*8, cl*8+8) = one uint2 (8 B) of the 128 B fp8 row.
// ---------------------------------------------------------------------------
__global__ __launch_bounds__(256) void k_gather(
    const int* __restrict__ offs, const unsigned* __restrict__ pairs,
    const unsigned* __restrict__ Af8u, unsigned* __restrict__ A1u) {
  int node = blockIdx.x * 4 + (threadIdx.x >> 6);
  if (node >= N_NODES) return;
  const int lane = threadIdx.x & 63;
  const int g = lane >> 4;
  const int cl = lane & 15;
  const int start = offs[node], end = offs[node + 1];
  const int deg = end - start;
  const unsigned* fbase = Af8u + cl * 2;

  float acc[8] = {0.f, 0.f, 0.f, 0.f, 0.f, 0.f, 0.f, 0.f};

  for (int k0 = start; k0 < end; k0 += 64) {
    unsigned pr = 0;
    if (k0 + lane < end) pr = pairs[k0 + lane];
    const int cnt = min(64, end - k0);
    const int nsteps = (cnt + 3) >> 2;
    for (int t = 0; t < nsteps; t += 2) {
      unsigned uu0 = (unsigned)__shfl((int)pr, 4 * t + g, 64);
      unsigned uu1 = (unsigned)__shfl((int)pr, 4 * (t + 1) + g, 64);
      int s0 = (int)(uu0 >> 15);
      int s1 = (int)(uu1 >> 15);
      float w0 = __half2float(__ushort_as_half((unsigned short)(uu0 & 0x7fffu)));
      float w1 = __half2float(__ushort_as_half((unsigned short)(uu1 & 0x7fffu)));
      uint2 f0 = *reinterpret_cast<const uint2*>(fbase + (size_t)s0 * 32);
      uint2 f1 = *reinterpret_cast<const uint2*>(fbase + (size_t)s1 * 32);
      acc[0] = fmaf(w0, FP8_DEC(f0.x, 0), acc[0]);
      acc[1] = fmaf(w0, FP8_DEC(f0.x, 1), acc[1]);
      acc[2] = fmaf(w0, FP8_DEC(f0.x, 2), acc[2]);
      acc[3] = fmaf(w0, FP8_DEC(f0.x, 3), acc[3]);
      acc[4] = fmaf(w0, FP8_DEC(f0.y, 0), acc[4]);
      acc[5] = fmaf(w0, FP8_DEC(f0.y, 1), acc[5]);
      acc[6] = fmaf(w0, FP8_DEC(f0.y, 2), acc[6]);
      acc[7] = fmaf(w0, FP8_DEC(f0.y, 3), acc[7]);
      acc[0] = fmaf(w1, FP8_DEC(f1.x, 0), acc[0]);
      acc[1] = fmaf(w1, FP8_DEC(f1.x, 1), acc[1]);
      acc[2] = fmaf(w1, FP8_DEC(f1.x, 2), acc[2]);
      acc[3] = fmaf(w1, FP8_DEC(f1.x, 3), acc[3]);
      acc[4] = fmaf(w1, FP8_DEC(f1.y, 0), acc[4]);
      acc[5] = fmaf(w1, FP8_DEC(f1.y, 1), acc[5]);
      acc[6] = fmaf(w1, FP8_DEC(f1.y, 2), acc[6]);
      acc[7] = fmaf(w1, FP8_DEC(f1.y, 3), acc[7]);
    }
  }

#pragma unroll
  for (int i = 0; i < 8; ++i) {
    acc[i] += __shfl_xor(acc[i], 16, 64);
    acc[i] += __shfl_xor(acc[i], 32, 64);
  }

  if (g == 0) {
    const float inv = (deg > 0) ? (1.0f / (float)deg) : 0.f;
    uint4 o;
    o.x = f2bf_pair(acc[0] * inv, acc[1] * inv);
    o.y = f2bf_pair(acc[2] * inv, acc[3] * inv);
    o.z = f2bf_pair(acc[4] * inv, acc[5] * inv);
    o.w = f2bf_pair(acc[6] * inv, acc[7] * inv);
    *reinterpret_cast<uint4*>(A1u + (size_t)node * 128 + 64 + cl * 4) = o;
  }
}

// ---------------------------------------------------------------------------
// K6: GEMM1, register-resident weights, persistent waves (validated round 8)
// ---------------------------------------------------------------------------
__global__ __launch_bounds__(256, 2) void k_gemm1(
    const unsigned short* __restrict__ A1, const unsigned short* __restrict__ W1T,
    const float* __restrict__ bias, unsigned short* __restrict__ y,
    float* __restrict__ colpart) {
  const int lane = threadIdx.x & 63;
  const int wid = threadIdx.x >> 6;
  const int l16 = lane & 15, lk = lane >> 4;
  const int h0 = wid * 64;

  bf16x8 wreg[8][4];
#pragma unroll
  for (int ks = 0; ks < 8; ++ks)
#pragma unroll
    for (int m = 0; m < 4; ++m)
      wreg[ks][m] = *reinterpret_cast<const bf16x8*>(
          W1T + (size_t)(h0 + m * 16 + l16) * 256 + ks * 32 + lk * 8);

  float4 bias4[4];
#pragma unroll
  for (int m = 0; m < 4; ++m)
    bias4[m] = *reinterpret_cast<const float4*>(bias + h0 + m * 16 + lk * 4);

  float sacc[4][4] = {};
  float qacc[4][4] = {};

  for (int t = blockIdx.x; t < NSUB; t += G1_GRID) {
    const int nbase = t * 32;
    f32x4 acc[4][2];
#pragma unroll
    for (int m = 0; m < 4; ++m)
#pragma unroll
      for (int n = 0; n < 2; ++n) acc[m][n] = (f32x4){0.f, 0.f, 0.f, 0.f};

#pragma unroll
    for (int ks = 0; ks < 8; ++ks) {
      bf16x8 bf0 = *reinterpret_cast<const bf16x8*>(
          A1 + (size_t)(nbase + l16) * 256 + ks * 32 + lk * 8);
      bf16x8 bf1 = *reinterpret_cast<const bf16x8*>(
          A1 + (size_t)(nbase + 16 + l16) * 256 + ks * 32 + lk * 8);
#pragma unroll
      for (int m = 0; m < 4; ++m) {
        acc[m][0] = __builtin_amdgcn_mfma_f32_16x16x32_bf16(
            wreg[ks][m], bf0, acc[m][0], 0, 0, 0);
        acc[m][1] = __builtin_amdgcn_mfma_f32_16x16x32_bf16(
            wreg[ks][m], bf1, acc[m][1], 0, 0, 0);
      }
    }

#pragma unroll
    for (int m = 0; m < 4; ++m) {
#pragma unroll
      for (int n = 0; n < 2; ++n) {
        float t0 = fmaxf(acc[m][n][0] + bias4[m].x, 0.f);
        float t1 = fmaxf(acc[m][n][1] + bias4[m].y, 0.f);
        float t2 = fmaxf(acc[m][n][2] + bias4[m].z, 0.f);
        float t3 = fmaxf(acc[m][n][3] + bias4[m].w, 0.f);
        uint2 pk;
        pk.x = f2bf_pair(t0, t1);
        pk.y = f2bf_pair(t2, t3);
        *reinterpret_cast<uint2*>(
            y + (size_t)(nbase + n * 16 + l16) * 256 + h0 + m * 16 + lk * 4) = pk;
        sacc[m][0] += t0; sacc[m][1] += t1; sacc[m][2] += t2; sacc[m][3] += t3;
        qacc[m][0] = fmaf(t0, t0, qacc[m][0]);
        qacc[m][1] = fmaf(t1, t1, qacc[m][1]);
        qacc[m][2] = fmaf(t2, t2, qacc[m][2]);
        qacc[m][3] = fmaf(t3, t3, qacc[m][3]);
      }
    }
  }

#pragma unroll
  for (int m = 0; m < 4; ++m) {
#pragma unroll
    for (int r = 0; r < 4; ++r) {
      float s = sacc[m][r], q = qacc[m][r];
      s += __shfl_xor(s, 1, 64); s += __shfl_xor(s, 2, 64);
      s += __shfl_xor(s, 4, 64); s += __shfl_xor(s, 8, 64);
      q += __shfl_xor(q, 1, 64); q += __shfl_xor(q, 2, 64);
      q += __shfl_xor(q, 4, 64); q += __shfl_xor(q, 8, 64);
      if (l16 == 0) {
        int h = h0 + m * 16 + lk * 4 + r;
        colpart[(size_t)blockIdx.x * 512 + h] = s;
        colpart[(size_t)blockIdx.x * 512 + 256 + h] = q;
      }
    }
  }
}

// ---------------------------------------------------------------------------
// K6b: reduce colpart slab -> colsum/colsq (pre-zeroed)
// ---------------------------------------------------------------------------
__global__ __launch_bounds__(256) void k_redstats(
    const float* __restrict__ colpart, float* __restrict__ colsum,
    float* __restrict__ colsq) {
  const int h = threadIdx.x;
  float s = 0.f, q = 0.f;
  for (int j = blockIdx.x; j < G1_GRID; j += gridDim.x) {
    s += colpart[(size_t)j * 512 + h];
    q += colpart[(size_t)j * 512 + 256 + h];
  }
  atomicAdd(&colsum[h], s);
  atomicAdd(&colsq[h], q);
}

// ---------------------------------------------------------------------------
// K7: BN fold -> W2T[o][h] bf16 (o padded to 192), b2[o] f32
// ---------------------------------------------------------------------------
__global__ __launch_bounds__(256) void k_finalize(
    const float* __restrict__ colsum, const float* __restrict__ colsq,
    const float* __restrict__ gamma, const float* __restrict__ beta,
    const float* __restrict__ fcW, const float* __restrict__ fcb,
    unsigned short* __restrict__ W2T, float* __restrict__ b2) {
  const float invN = 1.0f / (float)N_NODES;
  if (blockIdx.x < 192) {
    int o = blockIdx.x, h = threadIdx.x;
    unsigned short v = 0;
    if (o < OUT_F) {
      float mu = colsum[h] * invN;
      float var = colsq[h] * invN - mu * mu;
      float rs = rsqrtf(var + BN_EPS) * gamma[h];
      v = f2bf(fcW[(size_t)h * OUT_F + o] * rs);
    }
    W2T[(size_t)o * 256 + h] = v;
  } else if (threadIdx.x < OUT_F) {
    int o = threadIdx.x;
    float acc = fcb[o];
    for (int h = 0; h < HID_F; ++h) {
      float mu = colsum[h] * invN;
      float var = colsq[h] * invN - mu * mu;
      float rs = rsqrtf(var + BN_EPS) * gamma[h];
      acc += (beta[h] - mu * rs) * fcW[(size_t)h * OUT_F + o];
    }
    b2[o] = acc;
  }
}

// ---------------------------------------------------------------------------
// K8: GEMM2, register-resident weights, persistent waves (validated round 8)
// ---------------------------------------------------------------------------
__global__ __launch_bounds__(256, 2) void k_gemm2(
    const unsigned short* __restrict__ y, const unsigned short* __restrict__ W2T,
    const float* __restrict__ b2, float* __restrict__ out) {
  const int lane = threadIdx.x & 63;
  const int wid = threadIdx.x >> 6;
  const int l16 = lane & 15, lk = lane >> 4;
  const int wn = wid & 1;
  const int o0 = (wid >> 1) * 80;

  bf16x8 wreg[8][5];
#pragma unroll
  for (int ks = 0; ks < 8; ++ks)
#pragma unroll
    for (int m = 0; m < 5; ++m)
      wreg[ks][m] = *reinterpret_cast<const bf16x8*>(
          W2T + (size_t)(o0 + m * 16 + l16) * 256 + ks * 32 + lk * 8);

  float4 b24[5];
#pragma unroll
  for (int m = 0; m < 5; ++m)
    b24[m] = *reinterpret_cast<const float4*>(b2 + o0 + m * 16 + lk * 4);

  for (int t = blockIdx.x; t < NT2; t += G2_GRID) {
    const int nb = t * 64 + wn * 32;
    const int r0 = min(nb + l16, N_NODES - 1);
    const int r1 = min(nb + 16 + l16, N_NODES - 1);

    f32x4 acc[5][2];
#pragma unroll
    for (int m = 0; m < 5; ++m)
#pragma unroll
      for (int n = 0; n < 2; ++n) acc[m][n] = (f32x4){0.f, 0.f, 0.f, 0.f};

#pragma unroll
    for (int ks = 0; ks < 8; ++ks) {
      bf16x8 bf0 = *reinterpret_cast<const bf16x8*>(
          y + (size_t)r0 * 256 + ks * 32 + lk * 8);
      bf16x8 bf1 = *reinterpret_cast<const bf16x8*>(
          y + (size_t)r1 * 256 + ks * 32 + lk * 8);
#pragma unroll
      for (int m = 0; m < 5; ++m) {
        acc[m][0] = __builtin_amdgcn_mfma_f32_16x16x32_bf16(
            wreg[ks][m], bf0, acc[m][0], 0, 0, 0);
        acc[m][1] = __builtin_amdgcn_mfma_f32_16x16x32_bf16(
            wreg[ks][m], bf1, acc[m][1], 0, 0, 0);
      }
    }

#pragma unroll
    for (int n = 0; n < 2; ++n) {
      const int fb = nb + n * 16;
      if (fb < N_NODES) {
#pragma unroll
        for (int m = 0; m < 5; ++m) {
          float4 v;
          v.x = acc[m][n][0] + b24[m].x;
          v.y = acc[m][n][1] + b24[m].y;
          v.z = acc[m][n][2] + b24[m].z;
          v.w = acc[m][n][3] + b24[m].w;
          *reinterpret_cast<float4*>(
              out + (size_t)(fb + l16) * OUT_F + o0 + m * 16 + lk * 4) = v;
        }
      }
    }
  }
}

// ---------------------------------------------------------------------------
extern "C" void kernel_launch(void* const* d_in, const int* in_sizes, int n_in,
                              void* d_out, int out_size, void* d_ws,
                              size_t ws_size, hipStream_t stream) {
  const float* feat   = (const float*)d_in[0];
  const int*   src    = (const int*)d_in[1];
  const int*   dst    = (const int*)d_in[2];
  const float* ew     = (const float*)d_in[3];
  const float* Wself  = (const float*)d_in[4];
  const float* Wneigh = (const float*)d_in[5];
  const float* bias   = (const float*)d_in[6];
  const float* gamma  = (const float*)d_in[7];
  const float* beta   = (const float*)d_in[8];
  const float* fcW    = (const float*)d_in[9];
  const float* fcb    = (const float*)d_in[10];
  float* out = (float*)d_out;

  char* ws = (char*)d_ws;
  // layout (bytes):
  //   [0,      1,024)      gcnt    256 i32         (zeroed)
  //   [1,024,  2,048)      colsum  256 f32         (zeroed)
  //   [2,048,  3,072)      colsq   256 f32         (zeroed)
  //   [4,224,  404,228)    offs    (N+1) i32
  //   [404,480, 6,804,480) pairs   E u32
  //   [6,804,480, 23,581,696)   bucket 256*8192 uint2
  //   [23,581,696, 36,381,696)  Af8    N*128 fp8
  //   [36,381,696, 87,581,696)  A1     N*256 bf16 (feat | neigh)
  //   [87,581,696, 87,712,768)  W1T    256*256 bf16
  //   [87,712,768, 87,811,072)  W2T    192*256 bf16
  //   [87,811,072, 87,811,712)  b2     160 f32
  //   [87,811,712, 139,011,712) y      N*256 bf16
  //   [139,011,712, 140,060,288) colpart 512*512 f32
  int*            gcnt    = (int*)(ws + 0);
  float*          colsum  = (float*)(ws + 1024);
  float*          colsq   = (float*)(ws + 2048);
  int*            offs    = (int*)(ws + 4224);
  unsigned*       pairs   = (unsigned*)(ws + 404480);
  uint2*          bucket  = (uint2*)(ws + 6804480);
  unsigned*       Af8u    = (unsigned*)(ws + 23581696);
  unsigned*       A1u     = (unsigned*)(ws + 36381696);
  unsigned short* A1      = (unsigned short*)(ws + 36381696);
  unsigned short* W1T     = (unsigned short*)(ws + 87581696);
  unsigned short* W2T     = (unsigned short*)(ws + 87712768);
  float*          b2      = (float*)(ws + 87811072);
  unsigned short* y       = (unsigned short*)(ws + 87811712);
  float*          colpart = (float*)(ws + 139011712);

  hipMemsetAsync(ws, 0, 3072, stream);

  dim3 b256(256);
  k_convert<<<dim3(CVT_BLOCKS + 256), b256, 0, stream>>>(
      feat, A1u, Af8u, Wself, Wneigh, W1T);
  k_bucket<<<dim3(NCHUNK), b256, 0, stream>>>(src, dst, ew, gcnt, bucket);
  k_csr<<<dim3(NBKT), b256, 0, stream>>>(bucket, gcnt, offs, pairs);
  k_gather<<<dim3((N_NODES + 3) / 4), b256, 0, stream>>>(
      offs, pairs, Af8u, A1u);
  k_gemm1<<<dim3(G1_GRID), b256, 0, stream>>>(A1, W1T, bias, y, colpart);
  k_redstats<<<dim3(32), b256, 0, stream>>>(colpart, colsum, colsq);
  k_finalize<<<dim3(193), b256, 0, stream>>>(
      colsum, colsq, gamma, beta, fcW, fcb, W2T, b2);
  k_gemm2<<<dim3(G2_GRID), b256, 0, stream>>>(y, W2T, b2, out);
}